// Round 1
// baseline (222.625 us; speedup 1.0000x reference)
//
#include <hip/hip_runtime.h>
#include <math.h>

#define BB 64
#define SS 400
#define F2H 512
#define HID 256
#define EMB 128
#define NGATE 1024
#define VOC 50000

__device__ __forceinline__ float sigm(float x) { return 1.0f / (1.0f + __expf(-x)); }

// ---------------- K1a: gates partial GEMM ----------------
// grid (16 g-tiles of 64, 4 k-splits of 96), 256 threads
// part[ks][b][g] = sum over k-range of A[b][k]*W[g][k]
__global__ __launch_bounds__(256) void k_gates(
    const int* __restrict__ word, const float* __restrict__ hidden,
    const float* __restrict__ embed, const float* __restrict__ W_ih,
    const float* __restrict__ W_hh, float* __restrict__ part)
{
    const int gt = blockIdx.x;          // g tile
    const int ks = blockIdx.y;          // k split
    const int tid = threadIdx.x;
    __shared__ float As[32 * 68];
    __shared__ float Bs[32 * 68];
    const int g0 = gt * 64;
    const int k0 = ks * 96;
    float acc[4][4];
#pragma unroll
    for (int i = 0; i < 4; ++i)
#pragma unroll
        for (int j = 0; j < 4; ++j) acc[i][j] = 0.0f;

    const int tb = tid >> 4;   // 0..15 -> b rows tb*4..+3
    const int tg = tid & 15;   // 0..15 -> g cols tg*4..+3
    const int srow = tid >> 3; // 0..31
    const int skk = (tid & 7) * 4;

    for (int c = 0; c < 3; ++c) {
        const int kc = k0 + c * 32;
        // stage A (64 x 32): A[b][k] = k<128 ? embed[word[b]][k] : hidden[b][k-128]
#pragma unroll
        for (int p = 0; p < 2; ++p) {
            int rr = srow + p * 32;
            int gk = kc + skk;
            float4 f;
            if (gk < EMB) {
                int w = word[rr];
                f = *(const float4*)&embed[w * EMB + gk];
            } else {
                f = *(const float4*)&hidden[rr * HID + gk - EMB];
            }
            As[(skk + 0) * 68 + rr] = f.x;
            As[(skk + 1) * 68 + rr] = f.y;
            As[(skk + 2) * 68 + rr] = f.z;
            As[(skk + 3) * 68 + rr] = f.w;
        }
        // stage B (64 x 32): W[g][k] = k<128 ? W_ih[g][k] : W_hh[g][k-128]
#pragma unroll
        for (int p = 0; p < 2; ++p) {
            int nn = srow + p * 32;
            int g = g0 + nn;
            int gk = kc + skk;
            float4 f;
            if (gk < EMB) f = *(const float4*)&W_ih[g * EMB + gk];
            else          f = *(const float4*)&W_hh[g * HID + gk - EMB];
            Bs[(skk + 0) * 68 + nn] = f.x;
            Bs[(skk + 1) * 68 + nn] = f.y;
            Bs[(skk + 2) * 68 + nn] = f.z;
            Bs[(skk + 3) * 68 + nn] = f.w;
        }
        __syncthreads();
#pragma unroll 8
        for (int k = 0; k < 32; ++k) {
            float4 a = *(const float4*)&As[k * 68 + tb * 4];
            float4 b = *(const float4*)&Bs[k * 68 + tg * 4];
            float av[4] = {a.x, a.y, a.z, a.w};
            float bv[4] = {b.x, b.y, b.z, b.w};
#pragma unroll
            for (int i = 0; i < 4; ++i)
#pragma unroll
                for (int j = 0; j < 4; ++j) acc[i][j] += av[i] * bv[j];
        }
        __syncthreads();
    }
    float* dst = part + ks * (BB * NGATE);
#pragma unroll
    for (int i = 0; i < 4; ++i) {
        int b = tb * 4 + i;
        float4 o = {acc[i][0], acc[i][1], acc[i][2], acc[i][3]};
        *(float4*)&dst[b * NGATE + g0 + tg * 4] = o;
    }
}

// ---------------- K1b: LSTM pointwise + hproj ----------------
// grid 64 (b), 256 threads
__global__ __launch_bounds__(256) void k_lstm(
    const float* __restrict__ part, const float* __restrict__ cell,
    const float* __restrict__ b_ih, const float* __restrict__ b_hh,
    const float* __restrict__ attn_W, const float* __restrict__ attn_b,
    float* __restrict__ h_out, float* __restrict__ c_out, float* __restrict__ hproj)
{
    const int b = blockIdx.x;
    const int u = threadIdx.x;
    __shared__ float hrow[HID];

    float gi = b_ih[u] + b_hh[u];
    float gf = b_ih[u + 256] + b_hh[u + 256];
    float gg = b_ih[u + 512] + b_hh[u + 512];
    float go = b_ih[u + 768] + b_hh[u + 768];
#pragma unroll
    for (int ks = 0; ks < 4; ++ks) {
        const float* p = part + ks * (BB * NGATE) + b * NGATE;
        gi += p[u];
        gf += p[u + 256];
        gg += p[u + 512];
        go += p[u + 768];
    }
    float c = sigm(gf) * cell[b * HID + u] + sigm(gi) * tanhf(gg);
    float h = tanhf(sigm(go) * tanhf(c));
    c_out[b * HID + u] = c;
    h_out[b * HID + u] = h;
    hrow[u] = h;
    __syncthreads();

    // hproj[b][u] = h_row . W_h[u] + attn_b[u];  W_h[u][k] = attn_W[u*768 + 512 + k]
    float acc = attn_b[u];
    const float* wr = attn_W + u * 768 + 512;
#pragma unroll 8
    for (int k = 0; k < HID; k += 4) {
        float4 w = *(const float4*)&wr[k];
        acc += hrow[k] * w.x + hrow[k + 1] * w.y + hrow[k + 2] * w.z + hrow[k + 3] * w.w;
    }
    hproj[b * HID + u] = acc;
}

// ---------------- K2: attention scores ----------------
// e[b][s] = sum_h v[h] * tanh( enc[b,s,:].W_enc[h,:] + hproj[b][h] )
// grid 400 (row tiles of 64 over M=25600), 256 threads
__global__ __launch_bounds__(256) void k_scores(
    const float* __restrict__ enc, const float* __restrict__ attn_W,
    const float* __restrict__ hproj, const float* __restrict__ vvec,
    float* __restrict__ e)
{
    const int r0 = blockIdx.x * 64;
    const int tid = threadIdx.x;
    __shared__ float As[32 * 68];    // [k][m]
    __shared__ float Bs[32 * 260];   // [k][n]
    const int tm = tid >> 5;   // 0..7
    const int tn = tid & 31;   // 0..31
    const int srow = tid >> 3;
    const int skk = (tid & 7) * 4;

    float acc[8][8];
#pragma unroll
    for (int i = 0; i < 8; ++i)
#pragma unroll
        for (int j = 0; j < 8; ++j) acc[i][j] = 0.0f;

    for (int kc = 0; kc < F2H; kc += 32) {
        // stage A: 64 rows x 32 k
#pragma unroll
        for (int p = 0; p < 2; ++p) {
            int rr = srow + p * 32;
            float4 f = *(const float4*)&enc[(size_t)(r0 + rr) * F2H + kc + skk];
            As[(skk + 0) * 68 + rr] = f.x;
            As[(skk + 1) * 68 + rr] = f.y;
            As[(skk + 2) * 68 + rr] = f.z;
            As[(skk + 3) * 68 + rr] = f.w;
        }
        // stage B: 256 h x 32 k  (W_enc[h][k] = attn_W[h*768+k], k<512)
#pragma unroll
        for (int p = 0; p < 8; ++p) {
            int nn = srow + p * 32;
            float4 f = *(const float4*)&attn_W[nn * 768 + kc + skk];
            Bs[(skk + 0) * 260 + nn] = f.x;
            Bs[(skk + 1) * 260 + nn] = f.y;
            Bs[(skk + 2) * 260 + nn] = f.z;
            Bs[(skk + 3) * 260 + nn] = f.w;
        }
        __syncthreads();
#pragma unroll 8
        for (int k = 0; k < 32; ++k) {
            float4 a0 = *(const float4*)&As[k * 68 + tm * 4];
            float4 a1 = *(const float4*)&As[k * 68 + tm * 4 + 32];
            float4 b0 = *(const float4*)&Bs[k * 260 + tn * 4];
            float4 b1 = *(const float4*)&Bs[k * 260 + tn * 4 + 128];
            float av[8] = {a0.x, a0.y, a0.z, a0.w, a1.x, a1.y, a1.z, a1.w};
            float bv[8] = {b0.x, b0.y, b0.z, b0.w, b1.x, b1.y, b1.z, b1.w};
#pragma unroll
            for (int i = 0; i < 8; ++i)
#pragma unroll
                for (int j = 0; j < 8; ++j) acc[i][j] += av[i] * bv[j];
        }
        __syncthreads();
    }

    // epilogue: add hproj, tanh, dot v, reduce over 32 tn-lanes
    float vv[8];
    int hcol[8];
#pragma unroll
    for (int j = 0; j < 8; ++j) {
        hcol[j] = tn * 4 + (j & 3) + (j >> 2) * 128;
        vv[j] = vvec[hcol[j]];
    }
#pragma unroll
    for (int i = 0; i < 8; ++i) {
        int m = tm * 4 + (i & 3) + (i >> 2) * 32;
        int r = r0 + m;
        int b = r / SS;
        const float* hp = hproj + b * HID;
        float pp = 0.0f;
#pragma unroll
        for (int j = 0; j < 8; ++j)
            pp += vv[j] * tanhf(acc[i][j] + hp[hcol[j]]);
#pragma unroll
        for (int off = 16; off > 0; off >>= 1)
            pp += __shfl_xor(pp, off, 32);
        if (tn == 0) e[r] = pp;
    }
}

// ---------------- K3: softmax over s ----------------
// grid 64 (b), 512 threads
__global__ __launch_bounds__(512) void k_softmax(
    const float* __restrict__ e, float* __restrict__ att)
{
    const int b = blockIdx.x;
    const int tid = threadIdx.x;
    __shared__ float red[8];
    __shared__ float bmax, bsum;
    float x = (tid < SS) ? e[b * SS + tid] : -1e30f;
    float m = x;
#pragma unroll
    for (int off = 32; off > 0; off >>= 1) m = fmaxf(m, __shfl_xor(m, off));
    if ((tid & 63) == 0) red[tid >> 6] = m;
    __syncthreads();
    if (tid == 0) {
        float mm = red[0];
#pragma unroll
        for (int w = 1; w < 8; ++w) mm = fmaxf(mm, red[w]);
        bmax = mm;
    }
    __syncthreads();
    float p = (tid < SS) ? __expf(x - bmax) : 0.0f;
    float s = p;
#pragma unroll
    for (int off = 32; off > 0; off >>= 1) s += __shfl_xor(s, off);
    if ((tid & 63) == 0) red[tid >> 6] = s;
    __syncthreads();
    if (tid == 0) {
        float ss = 0.0f;
#pragma unroll
        for (int w = 0; w < 8; ++w) ss += red[w];
        bsum = ss;
    }
    __syncthreads();
    if (tid < SS) att[b * SS + tid] = p / bsum;
}

// ---------------- K4: context partial ----------------
// grid (64 b, 8 s-splits of 50), 512 threads (f)
__global__ __launch_bounds__(512) void k_context(
    const float* __restrict__ enc, const float* __restrict__ att,
    float* __restrict__ ctxp)
{
    const int b = blockIdx.x;
    const int sp = blockIdx.y;
    const int f = threadIdx.x;
    __shared__ float a_s[50];
    const int s0 = sp * 50;
    if (f < 50) a_s[f] = att[b * SS + s0 + f];
    __syncthreads();
    float acc = 0.0f;
    const float* ep = enc + ((size_t)(b * SS + s0)) * F2H + f;
#pragma unroll 5
    for (int s = 0; s < 50; ++s) acc += a_s[s] * ep[(size_t)s * F2H];
    ctxp[(sp * BB + b) * F2H + f] = acc;
}

// ---------------- K5: concat + projection ----------------
// grid 64 (b), 256 threads (out unit j)
__global__ __launch_bounds__(256) void k_catp(
    const float* __restrict__ ctxp, const float* __restrict__ hvals,
    const float* __restrict__ proj_W, const float* __restrict__ proj_b,
    float* __restrict__ catp)
{
    const int b = blockIdx.x;
    const int j = threadIdx.x;
    __shared__ float cat[768];
#pragma unroll
    for (int f = j; f < F2H; f += 256) {
        float s = 0.0f;
#pragma unroll
        for (int sp = 0; sp < 8; ++sp) s += ctxp[(sp * BB + b) * F2H + f];
        cat[f] = s;
    }
    cat[F2H + j] = hvals[b * HID + j];
    __syncthreads();
    float acc = proj_b[j];
    const float* wr = proj_W + j * 768;
#pragma unroll 8
    for (int k = 0; k < 768; k += 4) {
        float4 w = *(const float4*)&wr[k];
        acc += cat[k] * w.x + cat[k + 1] * w.y + cat[k + 2] * w.z + cat[k + 3] * w.w;
    }
    catp[b * HID + j] = acc;
}

// ---------------- K6: output GEMM ----------------
// wd[b][v] = catp[b][:].out_W[v][:] + out_b[v]
// grid 391 (v tiles of 128), 256 threads; thread: 8 b x 4 v
__global__ __launch_bounds__(256) void k_out(
    const float* __restrict__ catp, const float* __restrict__ out_W,
    const float* __restrict__ out_b, float* __restrict__ wd)
{
    const int v0 = blockIdx.x * 128;
    const int tid = threadIdx.x;
    __shared__ float As[32 * 68];    // [k][b]
    __shared__ float Bs[32 * 132];   // [k][v]
    const int tm = tid >> 5;
    const int tn = tid & 31;
    const int srow = tid >> 3;
    const int skk = (tid & 7) * 4;

    float acc[8][4];
#pragma unroll
    for (int i = 0; i < 8; ++i)
#pragma unroll
        for (int j = 0; j < 4; ++j) acc[i][j] = 0.0f;

    for (int kc = 0; kc < HID; kc += 32) {
#pragma unroll
        for (int p = 0; p < 2; ++p) {
            int rr = srow + p * 32;
            float4 f = *(const float4*)&catp[rr * HID + kc + skk];
            As[(skk + 0) * 68 + rr] = f.x;
            As[(skk + 1) * 68 + rr] = f.y;
            As[(skk + 2) * 68 + rr] = f.z;
            As[(skk + 3) * 68 + rr] = f.w;
        }
#pragma unroll
        for (int p = 0; p < 4; ++p) {
            int nn = srow + p * 32;
            int vr = v0 + nn;
            float4 f = {0.0f, 0.0f, 0.0f, 0.0f};
            if (vr < VOC) f = *(const float4*)&out_W[(size_t)vr * HID + kc + skk];
            Bs[(skk + 0) * 132 + nn] = f.x;
            Bs[(skk + 1) * 132 + nn] = f.y;
            Bs[(skk + 2) * 132 + nn] = f.z;
            Bs[(skk + 3) * 132 + nn] = f.w;
        }
        __syncthreads();
#pragma unroll 8
        for (int k = 0; k < 32; ++k) {
            float4 a0 = *(const float4*)&As[k * 68 + tm * 4];
            float4 a1 = *(const float4*)&As[k * 68 + tm * 4 + 32];
            float4 b0 = *(const float4*)&Bs[k * 132 + tn * 4];
            float av[8] = {a0.x, a0.y, a0.z, a0.w, a1.x, a1.y, a1.z, a1.w};
            float bv[4] = {b0.x, b0.y, b0.z, b0.w};
#pragma unroll
            for (int i = 0; i < 8; ++i)
#pragma unroll
                for (int j = 0; j < 4; ++j) acc[i][j] += av[i] * bv[j];
        }
        __syncthreads();
    }
    const int vc = v0 + tn * 4;
    if (vc < VOC) {
        float4 bias = *(const float4*)&out_b[vc];
#pragma unroll
        for (int i = 0; i < 8; ++i) {
            int m = tm * 4 + (i & 3) + (i >> 2) * 32;
            float4 o = {acc[i][0] + bias.x, acc[i][1] + bias.y,
                        acc[i][2] + bias.z, acc[i][3] + bias.w};
            *(float4*)&wd[(size_t)m * VOC + vc] = o;
        }
    }
}

extern "C" void kernel_launch(void* const* d_in, const int* in_sizes, int n_in,
                              void* d_out, int out_size, void* d_ws, size_t ws_size,
                              hipStream_t stream) {
    const int*   word   = (const int*)  d_in[0];
    const float* hidden = (const float*)d_in[1];
    const float* cell   = (const float*)d_in[2];
    const float* enc    = (const float*)d_in[3];
    const float* embed  = (const float*)d_in[5];
    const float* W_ih   = (const float*)d_in[6];
    const float* W_hh   = (const float*)d_in[7];
    const float* b_ih   = (const float*)d_in[8];
    const float* b_hh   = (const float*)d_in[9];
    const float* attn_W = (const float*)d_in[10];
    const float* attn_b = (const float*)d_in[11];
    const float* vvec   = (const float*)d_in[12];
    const float* proj_W = (const float*)d_in[13];
    const float* proj_b = (const float*)d_in[14];
    const float* out_W  = (const float*)d_in[15];
    const float* out_b  = (const float*)d_in[16];

    float* wd  = (float*)d_out;
    float* h_o = wd + (size_t)BB * VOC;
    float* c_o = h_o + BB * HID;

    float* ws    = (float*)d_ws;
    float* part  = ws;                  // 4*64*1024 = 262144
    float* hproj = part + 262144;       // 16384
    float* e     = hproj + 16384;       // 25600
    float* att   = e + 25600;           // 25600
    float* ctxp  = att + 25600;         // 8*64*512 = 262144
    float* catp  = ctxp + 262144;       // 16384

    k_gates<<<dim3(16, 4), 256, 0, stream>>>(word, hidden, embed, W_ih, W_hh, part);
    k_lstm<<<64, 256, 0, stream>>>(part, cell, b_ih, b_hh, attn_W, attn_b, h_o, c_o, hproj);
    k_scores<<<400, 256, 0, stream>>>(enc, attn_W, hproj, vvec, e);
    k_softmax<<<64, 512, 0, stream>>>(e, att);
    k_context<<<dim3(64, 8), 512, 0, stream>>>(enc, att, ctxp);
    k_catp<<<64, 256, 0, stream>>>(ctxp, h_o, proj_W, proj_b, catp);
    k_out<<<391, 256, 0, stream>>>(catp, out_W, out_b, wd);
}

// Round 2
// 125.534 us; speedup vs baseline: 1.7734x; 1.7734x over previous
//
#include <hip/hip_runtime.h>
#include <math.h>

#define BB 64
#define SS 400
#define F2H 512
#define HID 256
#define EMB 128
#define NGATE 1024
#define VOC 50000

typedef short bf16x8 __attribute__((ext_vector_type(8)));
typedef float f32x4 __attribute__((ext_vector_type(4)));

__device__ __forceinline__ float sigm(float x) { return 1.0f / (1.0f + __expf(-x)); }

__device__ __forceinline__ float ftanh(float x) {
    x = fminf(fmaxf(x, -15.0f), 15.0f);
    float t = __expf(2.0f * x);
    return (t - 1.0f) / (t + 1.0f);
}

__device__ __forceinline__ ushort f2bf(float x) {
    uint32_t u = __float_as_uint(x);
    uint32_t r = u + 0x7FFFu + ((u >> 16) & 1u);
    return (ushort)(r >> 16);
}

// ---------------- K0: bf16 prep ----------------
// blocks [0,1600): enc fp32 -> bf16 (13,107,200 elems)
// blocks [1600,1616): W_enc slice of attn_W -> wenc_bf [256][512]
__global__ __launch_bounds__(256) void k_prep(
    const float* __restrict__ enc, const float* __restrict__ attn_W,
    ushort* __restrict__ enc_bf, ushort* __restrict__ wenc_bf)
{
    const int blk = blockIdx.x;
    const int tid = threadIdx.x;
    if (blk < 1600) {
        const float4* src = (const float4*)enc;
        size_t i0 = (size_t)blk * 2048 + tid;
#pragma unroll
        for (int r = 0; r < 8; ++r) {
            size_t i = i0 + (size_t)r * 256;
            float4 f = src[i];
            ushort4 o = make_ushort4(f2bf(f.x), f2bf(f.y), f2bf(f.z), f2bf(f.w));
            ((ushort4*)enc_bf)[i] = o;
        }
    } else {
        int b2 = blk - 1600;
        int i0 = b2 * 2048 + tid;
#pragma unroll
        for (int r = 0; r < 8; ++r) {
            int i = i0 + r * 256;           // float4 index in [256][128]
            int row = i >> 7, c = i & 127;
            float4 f = *(const float4*)&attn_W[row * 768 + c * 4];
            ushort4 o = make_ushort4(f2bf(f.x), f2bf(f.y), f2bf(f.z), f2bf(f.w));
            ((ushort4*)wenc_bf)[i] = o;
        }
    }
}

// ---------------- K1a: gates partial GEMM (fp32, tiny) ----------------
__global__ __launch_bounds__(256) void k_gates(
    const int* __restrict__ word, const float* __restrict__ hidden,
    const float* __restrict__ embed, const float* __restrict__ W_ih,
    const float* __restrict__ W_hh, float* __restrict__ part)
{
    const int gt = blockIdx.x;
    const int ks = blockIdx.y;
    const int tid = threadIdx.x;
    __shared__ float As[32 * 68];
    __shared__ float Bs[32 * 68];
    const int g0 = gt * 64;
    const int k0 = ks * 96;
    float acc[4][4];
#pragma unroll
    for (int i = 0; i < 4; ++i)
#pragma unroll
        for (int j = 0; j < 4; ++j) acc[i][j] = 0.0f;

    const int tb = tid >> 4;
    const int tg = tid & 15;
    const int srow = tid >> 3;
    const int skk = (tid & 7) * 4;

    for (int c = 0; c < 3; ++c) {
        const int kc = k0 + c * 32;
#pragma unroll
        for (int p = 0; p < 2; ++p) {
            int rr = srow + p * 32;
            int gk = kc + skk;
            float4 f;
            if (gk < EMB) {
                int w = word[rr];
                f = *(const float4*)&embed[w * EMB + gk];
            } else {
                f = *(const float4*)&hidden[rr * HID + gk - EMB];
            }
            As[(skk + 0) * 68 + rr] = f.x;
            As[(skk + 1) * 68 + rr] = f.y;
            As[(skk + 2) * 68 + rr] = f.z;
            As[(skk + 3) * 68 + rr] = f.w;
        }
#pragma unroll
        for (int p = 0; p < 2; ++p) {
            int nn = srow + p * 32;
            int g = g0 + nn;
            int gk = kc + skk;
            float4 f;
            if (gk < EMB) f = *(const float4*)&W_ih[g * EMB + gk];
            else          f = *(const float4*)&W_hh[g * HID + gk - EMB];
            Bs[(skk + 0) * 68 + nn] = f.x;
            Bs[(skk + 1) * 68 + nn] = f.y;
            Bs[(skk + 2) * 68 + nn] = f.z;
            Bs[(skk + 3) * 68 + nn] = f.w;
        }
        __syncthreads();
#pragma unroll 8
        for (int k = 0; k < 32; ++k) {
            float4 a = *(const float4*)&As[k * 68 + tb * 4];
            float4 b = *(const float4*)&Bs[k * 68 + tg * 4];
            float av[4] = {a.x, a.y, a.z, a.w};
            float bv[4] = {b.x, b.y, b.z, b.w};
#pragma unroll
            for (int i = 0; i < 4; ++i)
#pragma unroll
                for (int j = 0; j < 4; ++j) acc[i][j] += av[i] * bv[j];
        }
        __syncthreads();
    }
    float* dst = part + ks * (BB * NGATE);
#pragma unroll
    for (int i = 0; i < 4; ++i) {
        int b = tb * 4 + i;
        float4 o = {acc[i][0], acc[i][1], acc[i][2], acc[i][3]};
        *(float4*)&dst[b * NGATE + g0 + tg * 4] = o;
    }
}

// ---------------- K1b: LSTM pointwise + hproj ----------------
__global__ __launch_bounds__(256) void k_lstm(
    const float* __restrict__ part, const float* __restrict__ cell,
    const float* __restrict__ b_ih, const float* __restrict__ b_hh,
    const float* __restrict__ attn_W, const float* __restrict__ attn_b,
    float* __restrict__ h_out, float* __restrict__ c_out, float* __restrict__ hproj)
{
    const int b = blockIdx.x;
    const int u = threadIdx.x;
    __shared__ float hrow[HID];

    float gi = b_ih[u] + b_hh[u];
    float gf = b_ih[u + 256] + b_hh[u + 256];
    float gg = b_ih[u + 512] + b_hh[u + 512];
    float go = b_ih[u + 768] + b_hh[u + 768];
#pragma unroll
    for (int ks = 0; ks < 4; ++ks) {
        const float* p = part + ks * (BB * NGATE) + b * NGATE;
        gi += p[u];
        gf += p[u + 256];
        gg += p[u + 512];
        go += p[u + 768];
    }
    float c = sigm(gf) * cell[b * HID + u] + sigm(gi) * tanhf(gg);
    float h = tanhf(sigm(go) * tanhf(c));
    c_out[b * HID + u] = c;
    h_out[b * HID + u] = h;
    hrow[u] = h;
    __syncthreads();

    float acc = attn_b[u];
    const float* wr = attn_W + u * 768 + 512;
#pragma unroll 8
    for (int k = 0; k < HID; k += 4) {
        float4 w = *(const float4*)&wr[k];
        acc += hrow[k] * w.x + hrow[k + 1] * w.y + hrow[k + 2] * w.z + hrow[k + 3] * w.w;
    }
    hproj[b * HID + u] = acc;
}

// ---------------- K2: attention scores via bf16 MFMA ----------------
// pre[m][n] = sum_k enc_bf[m][k] * wenc_bf[n][k];  e[m] = sum_n v[n]*tanh(pre + hproj[b(m)][n])
// M tile 64 x full N=256, K-chunk 64, 4 waves: wave = 32 rows x 128 cols
__global__ __launch_bounds__(256) void k_scores(
    const ushort* __restrict__ enc_bf, const ushort* __restrict__ wenc_bf,
    const float* __restrict__ hproj, const float* __restrict__ vvec,
    float* __restrict__ e)
{
    __shared__ ushort Asm[64 * 64];    // [row][64k] XOR-swizzled in 16B units
    __shared__ ushort Bsm[256 * 64];
    __shared__ float epart[64][2];

    const int tid = threadIdx.x;
    const int l = tid & 63;
    const int w = tid >> 6;
    const int wr = w >> 1, wc = w & 1;
    const int r0 = blockIdx.x * 64;

    f32x4 acc[2][8];
#pragma unroll
    for (int mf = 0; mf < 2; ++mf)
#pragma unroll
        for (int nf = 0; nf < 8; ++nf) acc[mf][nf] = (f32x4){0.f, 0.f, 0.f, 0.f};

    for (int kc = 0; kc < F2H; kc += 64) {
        // stage A: 64 rows x 128B -> 8 wave-issues (2/wave); linear dest, pre-swizzled src
#pragma unroll
        for (int i = 0; i < 2; ++i) {
            int s = (w * 2 + i) * 64 + l;          // 16B slot index
            int row = s >> 3, cp = s & 7;
            int cl = cp ^ (row & 7);
            const ushort* src = enc_bf + (size_t)(r0 + row) * F2H + kc + cl * 8;
            __builtin_amdgcn_global_load_lds(
                (const __attribute__((address_space(1))) uint32_t*)src,
                (__attribute__((address_space(3))) uint32_t*)(Asm + (w * 2 + i) * 512),
                16, 0, 0);
        }
        // stage B: 256 rows x 128B -> 32 wave-issues (8/wave)
#pragma unroll
        for (int i = 0; i < 8; ++i) {
            int s = (w * 8 + i) * 64 + l;
            int row = s >> 3, cp = s & 7;
            int cl = cp ^ (row & 7);
            const ushort* src = wenc_bf + (size_t)row * F2H + kc + cl * 8;
            __builtin_amdgcn_global_load_lds(
                (const __attribute__((address_space(1))) uint32_t*)src,
                (__attribute__((address_space(3))) uint32_t*)(Bsm + (w * 8 + i) * 512),
                16, 0, 0);
        }
        __syncthreads();   // drains vmcnt before use
#pragma unroll
        for (int ks = 0; ks < 2; ++ks) {
            bf16x8 af[2], bfr[8];
#pragma unroll
            for (int mf = 0; mf < 2; ++mf) {
                int row = wr * 32 + mf * 16 + (l & 15);
                int c = ks * 4 + (l >> 4);
                af[mf] = *(const bf16x8*)&Asm[row * 64 + ((c ^ (row & 7)) * 8)];
            }
#pragma unroll
            for (int nf = 0; nf < 8; ++nf) {
                int row = wc * 128 + nf * 16 + (l & 15);
                int c = ks * 4 + (l >> 4);
                bfr[nf] = *(const bf16x8*)&Bsm[row * 64 + ((c ^ (row & 7)) * 8)];
            }
#pragma unroll
            for (int mf = 0; mf < 2; ++mf)
#pragma unroll
                for (int nf = 0; nf < 8; ++nf)
                    acc[mf][nf] = __builtin_amdgcn_mfma_f32_16x16x32_bf16(
                        af[mf], bfr[nf], acc[mf][nf], 0, 0, 0);
        }
        __syncthreads();
    }

    // epilogue: + hproj, tanh, dot v, reduce 16 lanes sharing each row
    float vv[8];
#pragma unroll
    for (int nf = 0; nf < 8; ++nf) vv[nf] = vvec[wc * 128 + nf * 16 + (l & 15)];

#pragma unroll
    for (int mf = 0; mf < 2; ++mf) {
#pragma unroll
        for (int r = 0; r < 4; ++r) {
            int row = wr * 32 + mf * 16 + (l >> 4) * 4 + r;
            int grow = r0 + row;
            int b = grow / SS;
            const float* hp = hproj + b * HID;
            float p = 0.0f;
#pragma unroll
            for (int nf = 0; nf < 8; ++nf) {
                int col = wc * 128 + nf * 16 + (l & 15);
                p += vv[nf] * ftanh(acc[mf][nf][r] + hp[col]);
            }
#pragma unroll
            for (int off = 8; off >= 1; off >>= 1) p += __shfl_xor(p, off);
            if ((l & 15) == 0) epart[row][wc] = p;
        }
    }
    __syncthreads();
    if (tid < 64) e[r0 + tid] = epart[tid][0] + epart[tid][1];
}

// ---------------- K3: softmax over s ----------------
__global__ __launch_bounds__(512) void k_softmax(
    const float* __restrict__ e, float* __restrict__ att)
{
    const int b = blockIdx.x;
    const int tid = threadIdx.x;
    __shared__ float red[8];
    __shared__ float bmax, bsum;
    float x = (tid < SS) ? e[b * SS + tid] : -1e30f;
    float m = x;
#pragma unroll
    for (int off = 32; off > 0; off >>= 1) m = fmaxf(m, __shfl_xor(m, off));
    if ((tid & 63) == 0) red[tid >> 6] = m;
    __syncthreads();
    if (tid == 0) {
        float mm = red[0];
#pragma unroll
        for (int w = 1; w < 8; ++w) mm = fmaxf(mm, red[w]);
        bmax = mm;
    }
    __syncthreads();
    float p = (tid < SS) ? __expf(x - bmax) : 0.0f;
    float s = p;
#pragma unroll
    for (int off = 32; off > 0; off >>= 1) s += __shfl_xor(s, off);
    if ((tid & 63) == 0) red[tid >> 6] = s;
    __syncthreads();
    if (tid == 0) {
        float ss = 0.0f;
#pragma unroll
        for (int w = 0; w < 8; ++w) ss += red[w];
        bsum = ss;
    }
    __syncthreads();
    if (tid < SS) att[b * SS + tid] = p / bsum;
}

// ---------------- K4: context partial (bf16 enc) ----------------
// grid (64 b, 8 s-splits of 50), 256 threads, 2 f per thread
__global__ __launch_bounds__(256) void k_context(
    const ushort* __restrict__ enc_bf, const float* __restrict__ att,
    float* __restrict__ ctxp)
{
    const int b = blockIdx.x;
    const int sp = blockIdx.y;
    const int t = threadIdx.x;
    __shared__ float a_s[50];
    const int s0 = sp * 50;
    if (t < 50) a_s[t] = att[b * SS + s0 + t];
    __syncthreads();
    float acc0 = 0.0f, acc1 = 0.0f;
    const ushort* ep = enc_bf + ((size_t)(b * SS + s0)) * F2H + t * 2;
#pragma unroll 5
    for (int s = 0; s < 50; ++s) {
        uint32_t u = *(const uint32_t*)(ep + (size_t)s * F2H);
        float f0 = __uint_as_float((u & 0xFFFFu) << 16);
        float f1 = __uint_as_float((u >> 16) << 16);
        float a = a_s[s];
        acc0 += a * f0;
        acc1 += a * f1;
    }
    float2 o = {acc0, acc1};
    *(float2*)&ctxp[((size_t)(sp * BB + b)) * F2H + t * 2] = o;
}

// ---------------- K5: concat + projection ----------------
__global__ __launch_bounds__(256) void k_catp(
    const float* __restrict__ ctxp, const float* __restrict__ hvals,
    const float* __restrict__ proj_W, const float* __restrict__ proj_b,
    float* __restrict__ catp)
{
    const int b = blockIdx.x;
    const int j = threadIdx.x;
    __shared__ float cat[768];
#pragma unroll
    for (int f = j; f < F2H; f += 256) {
        float s = 0.0f;
#pragma unroll
        for (int sp = 0; sp < 8; ++sp) s += ctxp[(sp * BB + b) * F2H + f];
        cat[f] = s;
    }
    cat[F2H + j] = hvals[b * HID + j];
    __syncthreads();
    float acc = proj_b[j];
    const float* wr = proj_W + j * 768;
#pragma unroll 8
    for (int k = 0; k < 768; k += 4) {
        float4 w = *(const float4*)&wr[k];
        acc += cat[k] * w.x + cat[k + 1] * w.y + cat[k + 2] * w.z + cat[k + 3] * w.w;
    }
    catp[b * HID + j] = acc;
}

// ---------------- K6: output GEMM (fp32) ----------------
__global__ __launch_bounds__(256) void k_out(
    const float* __restrict__ catp, const float* __restrict__ out_W,
    const float* __restrict__ out_b, float* __restrict__ wd)
{
    const int v0 = blockIdx.x * 128;
    const int tid = threadIdx.x;
    __shared__ float As[32 * 68];
    __shared__ float Bs[32 * 132];
    const int tm = tid >> 5;
    const int tn = tid & 31;
    const int srow = tid >> 3;
    const int skk = (tid & 7) * 4;

    float acc[8][4];
#pragma unroll
    for (int i = 0; i < 8; ++i)
#pragma unroll
        for (int j = 0; j < 4; ++j) acc[i][j] = 0.0f;

    for (int kc = 0; kc < HID; kc += 32) {
#pragma unroll
        for (int p = 0; p < 2; ++p) {
            int rr = srow + p * 32;
            float4 f = *(const float4*)&catp[rr * HID + kc + skk];
            As[(skk + 0) * 68 + rr] = f.x;
            As[(skk + 1) * 68 + rr] = f.y;
            As[(skk + 2) * 68 + rr] = f.z;
            As[(skk + 3) * 68 + rr] = f.w;
        }
#pragma unroll
        for (int p = 0; p < 4; ++p) {
            int nn = srow + p * 32;
            int vr = v0 + nn;
            float4 f = {0.0f, 0.0f, 0.0f, 0.0f};
            if (vr < VOC) f = *(const float4*)&out_W[(size_t)vr * HID + kc + skk];
            Bs[(skk + 0) * 132 + nn] = f.x;
            Bs[(skk + 1) * 132 + nn] = f.y;
            Bs[(skk + 2) * 132 + nn] = f.z;
            Bs[(skk + 3) * 132 + nn] = f.w;
        }
        __syncthreads();
#pragma unroll 8
        for (int k = 0; k < 32; ++k) {
            float4 a0 = *(const float4*)&As[k * 68 + tm * 4];
            float4 a1 = *(const float4*)&As[k * 68 + tm * 4 + 32];
            float4 b0 = *(const float4*)&Bs[k * 132 + tn * 4];
            float av[8] = {a0.x, a0.y, a0.z, a0.w, a1.x, a1.y, a1.z, a1.w};
            float bv[4] = {b0.x, b0.y, b0.z, b0.w};
#pragma unroll
            for (int i = 0; i < 8; ++i)
#pragma unroll
                for (int j = 0; j < 4; ++j) acc[i][j] += av[i] * bv[j];
        }
        __syncthreads();
    }
    const int vc = v0 + tn * 4;
    if (vc < VOC) {
        float4 bias = *(const float4*)&out_b[vc];
#pragma unroll
        for (int i = 0; i < 8; ++i) {
            int m = tm * 4 + (i & 3) + (i >> 2) * 32;
            float4 o = {acc[i][0] + bias.x, acc[i][1] + bias.y,
                        acc[i][2] + bias.z, acc[i][3] + bias.w};
            *(float4*)&wd[(size_t)m * VOC + vc] = o;
        }
    }
}

extern "C" void kernel_launch(void* const* d_in, const int* in_sizes, int n_in,
                              void* d_out, int out_size, void* d_ws, size_t ws_size,
                              hipStream_t stream) {
    const int*   word   = (const int*)  d_in[0];
    const float* hidden = (const float*)d_in[1];
    const float* cell   = (const float*)d_in[2];
    const float* enc    = (const float*)d_in[3];
    const float* embed  = (const float*)d_in[5];
    const float* W_ih   = (const float*)d_in[6];
    const float* W_hh   = (const float*)d_in[7];
    const float* b_ih   = (const float*)d_in[8];
    const float* b_hh   = (const float*)d_in[9];
    const float* attn_W = (const float*)d_in[10];
    const float* attn_b = (const float*)d_in[11];
    const float* vvec   = (const float*)d_in[12];
    const float* proj_W = (const float*)d_in[13];
    const float* proj_b = (const float*)d_in[14];
    const float* out_W  = (const float*)d_in[15];
    const float* out_b  = (const float*)d_in[16];

    float* wd  = (float*)d_out;
    float* h_o = wd + (size_t)BB * VOC;
    float* c_o = h_o + BB * HID;

    float* ws    = (float*)d_ws;
    float* part  = ws;                  // 4*64*1024 = 262144
    float* hproj = part + 262144;       // 16384
    float* e     = hproj + 16384;       // 25600
    float* att   = e + 25600;           // 25600
    float* ctxp  = att + 25600;         // 8*64*512 = 262144
    float* catp  = ctxp + 262144;       // 16384
    ushort* enc_bf  = (ushort*)(catp + 16384);   // 13,107,200 ushorts
    ushort* wenc_bf = enc_bf + (size_t)BB * SS * F2H;  // 131072 ushorts

    k_prep<<<1616, 256, 0, stream>>>(enc, attn_W, enc_bf, wenc_bf);
    k_gates<<<dim3(16, 4), 256, 0, stream>>>(word, hidden, embed, W_ih, W_hh, part);
    k_lstm<<<64, 256, 0, stream>>>(part, cell, b_ih, b_hh, attn_W, attn_b, h_o, c_o, hproj);
    k_scores<<<400, 256, 0, stream>>>(enc_bf, wenc_bf, hproj, vvec, e);
    k_softmax<<<64, 512, 0, stream>>>(e, att);
    k_context<<<dim3(64, 8), 256, 0, stream>>>(enc_bf, att, ctxp);
    k_catp<<<64, 256, 0, stream>>>(ctxp, h_o, proj_W, proj_b, catp);
    k_out<<<391, 256, 0, stream>>>(catp, out_W, out_b, wd);
}

// Round 3
// 102.159 us; speedup vs baseline: 2.1792x; 1.2288x over previous
//
#include <hip/hip_runtime.h>
#include <math.h>

#define BB 64
#define SS 400
#define F2H 512
#define HID 256
#define EMB 128
#define NGATE 1024
#define VOC 50000

typedef short bf16x8 __attribute__((ext_vector_type(8)));
typedef float f32x4 __attribute__((ext_vector_type(4)));

__device__ __forceinline__ float sigm(float x) { return 1.0f / (1.0f + __expf(-x)); }

__device__ __forceinline__ float ftanh(float x) {
    x = fminf(fmaxf(x, -15.0f), 15.0f);
    float t = __expf(2.0f * x);
    return (t - 1.0f) / (t + 1.0f);
}

__device__ __forceinline__ ushort f2bf(float x) {
    uint32_t u = __float_as_uint(x);
    uint32_t r = u + 0x7FFFu + ((u >> 16) & 1u);
    return (ushort)(r >> 16);
}

// ---------------- K0: bf16 prep ----------------
__global__ __launch_bounds__(256) void k_prep(
    const float* __restrict__ enc, const float* __restrict__ attn_W,
    ushort* __restrict__ enc_bf, ushort* __restrict__ wenc_bf)
{
    const int blk = blockIdx.x;
    const int tid = threadIdx.x;
    if (blk < 1600) {
        const float4* src = (const float4*)enc;
        size_t i0 = (size_t)blk * 2048 + tid;
#pragma unroll
        for (int r = 0; r < 8; ++r) {
            size_t i = i0 + (size_t)r * 256;
            float4 f = src[i];
            ushort4 o = make_ushort4(f2bf(f.x), f2bf(f.y), f2bf(f.z), f2bf(f.w));
            ((ushort4*)enc_bf)[i] = o;
        }
    } else {
        int b2 = blk - 1600;
        int i0 = b2 * 2048 + tid;
#pragma unroll
        for (int r = 0; r < 8; ++r) {
            int i = i0 + r * 256;
            int row = i >> 7, c = i & 127;
            float4 f = *(const float4*)&attn_W[row * 768 + c * 4];
            ushort4 o = make_ushort4(f2bf(f.x), f2bf(f.y), f2bf(f.z), f2bf(f.w));
            ((ushort4*)wenc_bf)[i] = o;
        }
    }
}

// ---------------- K1a: gates partial GEMM (fp32, tiny) ----------------
__global__ __launch_bounds__(256) void k_gates(
    const int* __restrict__ word, const float* __restrict__ hidden,
    const float* __restrict__ embed, const float* __restrict__ W_ih,
    const float* __restrict__ W_hh, float* __restrict__ part)
{
    const int gt = blockIdx.x;
    const int ks = blockIdx.y;
    const int tid = threadIdx.x;
    __shared__ float As[32 * 68];
    __shared__ float Bs[32 * 68];
    const int g0 = gt * 64;
    const int k0 = ks * 96;
    float acc[4][4];
#pragma unroll
    for (int i = 0; i < 4; ++i)
#pragma unroll
        for (int j = 0; j < 4; ++j) acc[i][j] = 0.0f;

    const int tb = tid >> 4;
    const int tg = tid & 15;
    const int srow = tid >> 3;
    const int skk = (tid & 7) * 4;

    for (int c = 0; c < 3; ++c) {
        const int kc = k0 + c * 32;
#pragma unroll
        for (int p = 0; p < 2; ++p) {
            int rr = srow + p * 32;
            int gk = kc + skk;
            float4 f;
            if (gk < EMB) {
                int w = word[rr];
                f = *(const float4*)&embed[w * EMB + gk];
            } else {
                f = *(const float4*)&hidden[rr * HID + gk - EMB];
            }
            As[(skk + 0) * 68 + rr] = f.x;
            As[(skk + 1) * 68 + rr] = f.y;
            As[(skk + 2) * 68 + rr] = f.z;
            As[(skk + 3) * 68 + rr] = f.w;
        }
#pragma unroll
        for (int p = 0; p < 2; ++p) {
            int nn = srow + p * 32;
            int g = g0 + nn;
            int gk = kc + skk;
            float4 f;
            if (gk < EMB) f = *(const float4*)&W_ih[g * EMB + gk];
            else          f = *(const float4*)&W_hh[g * HID + gk - EMB];
            Bs[(skk + 0) * 68 + nn] = f.x;
            Bs[(skk + 1) * 68 + nn] = f.y;
            Bs[(skk + 2) * 68 + nn] = f.z;
            Bs[(skk + 3) * 68 + nn] = f.w;
        }
        __syncthreads();
#pragma unroll 8
        for (int k = 0; k < 32; ++k) {
            float4 a = *(const float4*)&As[k * 68 + tb * 4];
            float4 b = *(const float4*)&Bs[k * 68 + tg * 4];
            float av[4] = {a.x, a.y, a.z, a.w};
            float bv[4] = {b.x, b.y, b.z, b.w};
#pragma unroll
            for (int i = 0; i < 4; ++i)
#pragma unroll
                for (int j = 0; j < 4; ++j) acc[i][j] += av[i] * bv[j];
        }
        __syncthreads();
    }
    float* dst = part + ks * (BB * NGATE);
#pragma unroll
    for (int i = 0; i < 4; ++i) {
        int b = tb * 4 + i;
        float4 o = {acc[i][0], acc[i][1], acc[i][2], acc[i][3]};
        *(float4*)&dst[b * NGATE + g0 + tg * 4] = o;
    }
}

// ---------------- K1b: LSTM pointwise + hproj ----------------
__global__ __launch_bounds__(256) void k_lstm(
    const float* __restrict__ part, const float* __restrict__ cell,
    const float* __restrict__ b_ih, const float* __restrict__ b_hh,
    const float* __restrict__ attn_W, const float* __restrict__ attn_b,
    float* __restrict__ h_out, float* __restrict__ c_out, float* __restrict__ hproj)
{
    const int b = blockIdx.x;
    const int u = threadIdx.x;
    __shared__ float hrow[HID];

    float gi = b_ih[u] + b_hh[u];
    float gf = b_ih[u + 256] + b_hh[u + 256];
    float gg = b_ih[u + 512] + b_hh[u + 512];
    float go = b_ih[u + 768] + b_hh[u + 768];
#pragma unroll
    for (int ks = 0; ks < 4; ++ks) {
        const float* p = part + ks * (BB * NGATE) + b * NGATE;
        gi += p[u];
        gf += p[u + 256];
        gg += p[u + 512];
        go += p[u + 768];
    }
    float c = sigm(gf) * cell[b * HID + u] + sigm(gi) * tanhf(gg);
    float h = tanhf(sigm(go) * tanhf(c));
    c_out[b * HID + u] = c;
    h_out[b * HID + u] = h;
    hrow[u] = h;
    __syncthreads();

    float acc = attn_b[u];
    const float* wr = attn_W + u * 768 + 512;
#pragma unroll 8
    for (int k = 0; k < HID; k += 4) {
        float4 w = *(const float4*)&wr[k];
        acc += hrow[k] * w.x + hrow[k + 1] * w.y + hrow[k + 2] * w.z + hrow[k + 3] * w.w;
    }
    hproj[b * HID + u] = acc;
}

// ---------------- K2: attention scores via bf16 MFMA ----------------
__global__ __launch_bounds__(256) void k_scores(
    const ushort* __restrict__ enc_bf, const ushort* __restrict__ wenc_bf,
    const float* __restrict__ hproj, const float* __restrict__ vvec,
    float* __restrict__ e)
{
    __shared__ ushort Asm[64 * 64];
    __shared__ ushort Bsm[256 * 64];
    __shared__ float epart[64][2];

    const int tid = threadIdx.x;
    const int l = tid & 63;
    const int w = tid >> 6;
    const int wr = w >> 1, wc = w & 1;
    const int r0 = blockIdx.x * 64;

    f32x4 acc[2][8];
#pragma unroll
    for (int mf = 0; mf < 2; ++mf)
#pragma unroll
        for (int nf = 0; nf < 8; ++nf) acc[mf][nf] = (f32x4){0.f, 0.f, 0.f, 0.f};

    for (int kc = 0; kc < F2H; kc += 64) {
#pragma unroll
        for (int i = 0; i < 2; ++i) {
            int s = (w * 2 + i) * 64 + l;
            int row = s >> 3, cp = s & 7;
            int cl = cp ^ (row & 7);
            const ushort* src = enc_bf + (size_t)(r0 + row) * F2H + kc + cl * 8;
            __builtin_amdgcn_global_load_lds(
                (const __attribute__((address_space(1))) uint32_t*)src,
                (__attribute__((address_space(3))) uint32_t*)(Asm + (w * 2 + i) * 512),
                16, 0, 0);
        }
#pragma unroll
        for (int i = 0; i < 8; ++i) {
            int s = (w * 8 + i) * 64 + l;
            int row = s >> 3, cp = s & 7;
            int cl = cp ^ (row & 7);
            const ushort* src = wenc_bf + (size_t)row * F2H + kc + cl * 8;
            __builtin_amdgcn_global_load_lds(
                (const __attribute__((address_space(1))) uint32_t*)src,
                (__attribute__((address_space(3))) uint32_t*)(Bsm + (w * 8 + i) * 512),
                16, 0, 0);
        }
        __syncthreads();
#pragma unroll
        for (int ks = 0; ks < 2; ++ks) {
            bf16x8 af[2], bfr[8];
#pragma unroll
            for (int mf = 0; mf < 2; ++mf) {
                int row = wr * 32 + mf * 16 + (l & 15);
                int c = ks * 4 + (l >> 4);
                af[mf] = *(const bf16x8*)&Asm[row * 64 + ((c ^ (row & 7)) * 8)];
            }
#pragma unroll
            for (int nf = 0; nf < 8; ++nf) {
                int row = wc * 128 + nf * 16 + (l & 15);
                int c = ks * 4 + (l >> 4);
                bfr[nf] = *(const bf16x8*)&Bsm[row * 64 + ((c ^ (row & 7)) * 8)];
            }
#pragma unroll
            for (int mf = 0; mf < 2; ++mf)
#pragma unroll
                for (int nf = 0; nf < 8; ++nf)
                    acc[mf][nf] = __builtin_amdgcn_mfma_f32_16x16x32_bf16(
                        af[mf], bfr[nf], acc[mf][nf], 0, 0, 0);
        }
        __syncthreads();
    }

    float vv[8];
#pragma unroll
    for (int nf = 0; nf < 8; ++nf) vv[nf] = vvec[wc * 128 + nf * 16 + (l & 15)];

#pragma unroll
    for (int mf = 0; mf < 2; ++mf) {
#pragma unroll
        for (int r = 0; r < 4; ++r) {
            int row = wr * 32 + mf * 16 + (l >> 4) * 4 + r;
            int grow = r0 + row;
            int b = grow / SS;
            const float* hp = hproj + b * HID;
            float p = 0.0f;
#pragma unroll
            for (int nf = 0; nf < 8; ++nf) {
                int col = wc * 128 + nf * 16 + (l & 15);
                p += vv[nf] * ftanh(acc[mf][nf][r] + hp[col]);
            }
#pragma unroll
            for (int off = 8; off >= 1; off >>= 1) p += __shfl_xor(p, off);
            if ((l & 15) == 0) epart[row][wc] = p;
        }
    }
    __syncthreads();
    if (tid < 64) e[r0 + tid] = epart[tid][0] + epart[tid][1];
}

// ---------------- K3: softmax over s ----------------
__global__ __launch_bounds__(512) void k_softmax(
    const float* __restrict__ e, float* __restrict__ att)
{
    const int b = blockIdx.x;
    const int tid = threadIdx.x;
    __shared__ float red[8];
    __shared__ float bmax, bsum;
    float x = (tid < SS) ? e[b * SS + tid] : -1e30f;
    float m = x;
#pragma unroll
    for (int off = 32; off > 0; off >>= 1) m = fmaxf(m, __shfl_xor(m, off));
    if ((tid & 63) == 0) red[tid >> 6] = m;
    __syncthreads();
    if (tid == 0) {
        float mm = red[0];
#pragma unroll
        for (int w = 1; w < 8; ++w) mm = fmaxf(mm, red[w]);
        bmax = mm;
    }
    __syncthreads();
    float p = (tid < SS) ? __expf(x - bmax) : 0.0f;
    float s = p;
#pragma unroll
    for (int off = 32; off > 0; off >>= 1) s += __shfl_xor(s, off);
    if ((tid & 63) == 0) red[tid >> 6] = s;
    __syncthreads();
    if (tid == 0) {
        float ss = 0.0f;
#pragma unroll
        for (int w = 0; w < 8; ++w) ss += red[w];
        bsum = ss;
    }
    __syncthreads();
    if (tid < SS) att[b * SS + tid] = p / bsum;
}

// ---------------- K4: context partial (bf16 enc) ----------------
__global__ __launch_bounds__(256) void k_context(
    const ushort* __restrict__ enc_bf, const float* __restrict__ att,
    float* __restrict__ ctxp)
{
    const int b = blockIdx.x;
    const int sp = blockIdx.y;
    const int t = threadIdx.x;
    __shared__ float a_s[50];
    const int s0 = sp * 50;
    if (t < 50) a_s[t] = att[b * SS + s0 + t];
    __syncthreads();
    float acc0 = 0.0f, acc1 = 0.0f;
    const ushort* ep = enc_bf + ((size_t)(b * SS + s0)) * F2H + t * 2;
#pragma unroll 5
    for (int s = 0; s < 50; ++s) {
        uint32_t u = *(const uint32_t*)(ep + (size_t)s * F2H);
        float f0 = __uint_as_float((u & 0xFFFFu) << 16);
        float f1 = __uint_as_float((u >> 16) << 16);
        float a = a_s[s];
        acc0 += a * f0;
        acc1 += a * f1;
    }
    float2 o = {acc0, acc1};
    *(float2*)&ctxp[((size_t)(sp * BB + b)) * F2H + t * 2] = o;
}

// ---------------- K5: concat + projection ----------------
__global__ __launch_bounds__(256) void k_catp(
    const float* __restrict__ ctxp, const float* __restrict__ hvals,
    const float* __restrict__ proj_W, const float* __restrict__ proj_b,
    float* __restrict__ catp)
{
    const int b = blockIdx.x;
    const int j = threadIdx.x;
    __shared__ float cat[768];
#pragma unroll
    for (int f = j; f < F2H; f += 256) {
        float s = 0.0f;
#pragma unroll
        for (int sp = 0; sp < 8; ++sp) s += ctxp[(sp * BB + b) * F2H + f];
        cat[f] = s;
    }
    cat[F2H + j] = hvals[b * HID + j];
    __syncthreads();
    float acc = proj_b[j];
    const float* wr = proj_W + j * 768;
#pragma unroll 8
    for (int k = 0; k < 768; k += 4) {
        float4 w = *(const float4*)&wr[k];
        acc += cat[k] * w.x + cat[k + 1] * w.y + cat[k + 2] * w.z + cat[k + 3] * w.w;
    }
    catp[b * HID + j] = acc;
}

// ---------------- K6: output GEMM via bf16 MFMA ----------------
// wd[b][v] = catp[b][:].out_W[v][:] + out_b[v]
// m = b (catp rows from swizzled LDS), n = v (out_W rows, fp32->bf16 in regs)
// 391 blocks x 256 thr (4 waves); block v-tile 128, wave v-tile 32; K=256 in 8 steps
__global__ __launch_bounds__(256) void k_out(
    const float* __restrict__ catp, const float* __restrict__ out_W,
    const float* __restrict__ out_b, float* __restrict__ wd)
{
    __shared__ ushort Cs[64 * 256];   // catp bf16, rows b, 16B units XOR-swizzled

    const int tid = threadIdx.x;
    const int l = tid & 63;
    const int w = tid >> 6;

    // stage catp (fp32 64KB) -> bf16 swizzled LDS (32KB)
#pragma unroll
    for (int i = 0; i < 8; ++i) {
        int u = i * 256 + tid;           // 16B-unit index: 64 rows x 32 units
        int n = u >> 5, c16 = u & 31;
        const float4* src = (const float4*)&catp[n * HID + c16 * 8];
        float4 f0 = src[0], f1 = src[1];
        bf16x8 o;
        o[0] = (short)f2bf(f0.x); o[1] = (short)f2bf(f0.y);
        o[2] = (short)f2bf(f0.z); o[3] = (short)f2bf(f0.w);
        o[4] = (short)f2bf(f1.x); o[5] = (short)f2bf(f1.y);
        o[6] = (short)f2bf(f1.z); o[7] = (short)f2bf(f1.w);
        *(bf16x8*)&Cs[n * 256 + ((c16 ^ (n & 7)) * 8)] = o;
    }
    __syncthreads();

    const int vw = blockIdx.x * 128 + w * 32;     // wave's v base
    const int q = l >> 4;                         // k-quad
    const int ln = l & 15;

    f32x4 acc[4][2];
#pragma unroll
    for (int af = 0; af < 4; ++af)
#pragma unroll
        for (int nf = 0; nf < 2; ++nf) acc[af][nf] = (f32x4){0.f, 0.f, 0.f, 0.f};

    int vr[2];
#pragma unroll
    for (int nf = 0; nf < 2; ++nf) {
        int v = vw + nf * 16 + ln;
        vr[nf] = v < VOC ? v : VOC - 1;
    }

#pragma unroll
    for (int s = 0; s < 8; ++s) {
        const int k = s * 32 + q * 8;
        bf16x8 bfr[2];
#pragma unroll
        for (int nf = 0; nf < 2; ++nf) {
            const float4* p = (const float4*)&out_W[(size_t)vr[nf] * HID + k];
            float4 f0 = p[0], f1 = p[1];
            bf16x8 o;
            o[0] = (short)f2bf(f0.x); o[1] = (short)f2bf(f0.y);
            o[2] = (short)f2bf(f0.z); o[3] = (short)f2bf(f0.w);
            o[4] = (short)f2bf(f1.x); o[5] = (short)f2bf(f1.y);
            o[6] = (short)f2bf(f1.z); o[7] = (short)f2bf(f1.w);
            bfr[nf] = o;
        }
#pragma unroll
        for (int af = 0; af < 4; ++af) {
            int row = af * 16 + ln;
            int c16 = (s * 4 + q) ^ (row & 7);
            bf16x8 a = *(const bf16x8*)&Cs[row * 256 + c16 * 8];
#pragma unroll
            for (int nf = 0; nf < 2; ++nf)
                acc[af][nf] = __builtin_amdgcn_mfma_f32_16x16x32_bf16(
                    a, bfr[nf], acc[af][nf], 0, 0, 0);
        }
    }

    // C layout: col(n=v) = l&15, row(m=b within frag) = (l>>4)*4 + r
#pragma unroll
    for (int nf = 0; nf < 2; ++nf) {
        int v = vw + nf * 16 + ln;
        if (v < VOC) {
            float bias = out_b[v];
#pragma unroll
            for (int af = 0; af < 4; ++af) {
                int b = af * 16 + q * 4;
#pragma unroll
                for (int r = 0; r < 4; ++r)
                    wd[(size_t)(b + r) * VOC + v] = acc[af][nf][r] + bias;
            }
        }
    }
}

extern "C" void kernel_launch(void* const* d_in, const int* in_sizes, int n_in,
                              void* d_out, int out_size, void* d_ws, size_t ws_size,
                              hipStream_t stream) {
    const int*   word   = (const int*)  d_in[0];
    const float* hidden = (const float*)d_in[1];
    const float* cell   = (const float*)d_in[2];
    const float* enc    = (const float*)d_in[3];
    const float* embed  = (const float*)d_in[5];
    const float* W_ih   = (const float*)d_in[6];
    const float* W_hh   = (const float*)d_in[7];
    const float* b_ih   = (const float*)d_in[8];
    const float* b_hh   = (const float*)d_in[9];
    const float* attn_W = (const float*)d_in[10];
    const float* attn_b = (const float*)d_in[11];
    const float* vvec   = (const float*)d_in[12];
    const float* proj_W = (const float*)d_in[13];
    const float* proj_b = (const float*)d_in[14];
    const float* out_W  = (const float*)d_in[15];
    const float* out_b  = (const float*)d_in[16];

    float* wd  = (float*)d_out;
    float* h_o = wd + (size_t)BB * VOC;
    float* c_o = h_o + BB * HID;

    float* ws    = (float*)d_ws;
    float* part  = ws;
    float* hproj = part + 262144;
    float* e     = hproj + 16384;
    float* att   = e + 25600;
    float* ctxp  = att + 25600;
    float* catp  = ctxp + 262144;
    ushort* enc_bf  = (ushort*)(catp + 16384);
    ushort* wenc_bf = enc_bf + (size_t)BB * SS * F2H;

    k_prep<<<1616, 256, 0, stream>>>(enc, attn_W, enc_bf, wenc_bf);
    k_gates<<<dim3(16, 4), 256, 0, stream>>>(word, hidden, embed, W_ih, W_hh, part);
    k_lstm<<<64, 256, 0, stream>>>(part, cell, b_ih, b_hh, attn_W, attn_b, h_o, c_o, hproj);
    k_scores<<<400, 256, 0, stream>>>(enc_bf, wenc_bf, hproj, vvec, e);
    k_softmax<<<64, 512, 0, stream>>>(e, att);
    k_context<<<dim3(64, 8), 256, 0, stream>>>(enc_bf, att, ctxp);
    k_catp<<<64, 256, 0, stream>>>(ctxp, h_o, proj_W, proj_b, catp);
    k_out<<<391, 256, 0, stream>>>(catp, out_W, out_b, wd);
}

// Round 4
// 101.386 us; speedup vs baseline: 2.1958x; 1.0076x over previous
//
#include <hip/hip_runtime.h>
#include <math.h>

#define BB 64
#define SS 400
#define F2H 512
#define HID 256
#define EMB 128
#define NGATE 1024
#define VOC 50000
#define CH 128

typedef short bf16x8 __attribute__((ext_vector_type(8)));
typedef float f32x4 __attribute__((ext_vector_type(4)));

__device__ __forceinline__ float sigm(float x) { return 1.0f / (1.0f + __expf(-x)); }

__device__ __forceinline__ float ftanh(float x) {
    x = fminf(fmaxf(x, -15.0f), 15.0f);
    float t = __expf(2.0f * x);
    return (t - 1.0f) / (t + 1.0f);
}

__device__ __forceinline__ ushort f2bf(float x) {
    uint32_t u = __float_as_uint(x);
    uint32_t r = u + 0x7FFFu + ((u >> 16) & 1u);
    return (ushort)(r >> 16);
}

// ---------------- K0: wenc bf16 prep (W_enc slice of attn_W) ----------------
__global__ __launch_bounds__(256) void k_prepw(
    const float* __restrict__ attn_W, ushort* __restrict__ wenc_bf)
{
    const int blk = blockIdx.x;
    const int tid = threadIdx.x;
    int i0 = blk * 2048 + tid;
#pragma unroll
    for (int r = 0; r < 8; ++r) {
        int i = i0 + r * 256;             // float4 index in [256][128]
        int row = i >> 7, c = i & 127;
        float4 f = *(const float4*)&attn_W[row * 768 + c * 4];
        ushort4 o = make_ushort4(f2bf(f.x), f2bf(f.y), f2bf(f.z), f2bf(f.w));
        ((ushort4*)wenc_bf)[i] = o;
    }
}

// ---------------- K1a: gates partial GEMM (fp32, tiny) ----------------
__global__ __launch_bounds__(256) void k_gates(
    const int* __restrict__ word, const float* __restrict__ hidden,
    const float* __restrict__ embed, const float* __restrict__ W_ih,
    const float* __restrict__ W_hh, float* __restrict__ part)
{
    const int gt = blockIdx.x;
    const int ks = blockIdx.y;
    const int tid = threadIdx.x;
    __shared__ float As[32 * 68];
    __shared__ float Bs[32 * 68];
    const int g0 = gt * 64;
    const int k0 = ks * 96;
    float acc[4][4];
#pragma unroll
    for (int i = 0; i < 4; ++i)
#pragma unroll
        for (int j = 0; j < 4; ++j) acc[i][j] = 0.0f;

    const int tb = tid >> 4;
    const int tg = tid & 15;
    const int srow = tid >> 3;
    const int skk = (tid & 7) * 4;

    for (int c = 0; c < 3; ++c) {
        const int kc = k0 + c * 32;
#pragma unroll
        for (int p = 0; p < 2; ++p) {
            int rr = srow + p * 32;
            int gk = kc + skk;
            float4 f;
            if (gk < EMB) {
                int w = word[rr];
                f = *(const float4*)&embed[w * EMB + gk];
            } else {
                f = *(const float4*)&hidden[rr * HID + gk - EMB];
            }
            As[(skk + 0) * 68 + rr] = f.x;
            As[(skk + 1) * 68 + rr] = f.y;
            As[(skk + 2) * 68 + rr] = f.z;
            As[(skk + 3) * 68 + rr] = f.w;
        }
#pragma unroll
        for (int p = 0; p < 2; ++p) {
            int nn = srow + p * 32;
            int g = g0 + nn;
            int gk = kc + skk;
            float4 f;
            if (gk < EMB) f = *(const float4*)&W_ih[g * EMB + gk];
            else          f = *(const float4*)&W_hh[g * HID + gk - EMB];
            Bs[(skk + 0) * 68 + nn] = f.x;
            Bs[(skk + 1) * 68 + nn] = f.y;
            Bs[(skk + 2) * 68 + nn] = f.z;
            Bs[(skk + 3) * 68 + nn] = f.w;
        }
        __syncthreads();
#pragma unroll 8
        for (int k = 0; k < 32; ++k) {
            float4 a = *(const float4*)&As[k * 68 + tb * 4];
            float4 b = *(const float4*)&Bs[k * 68 + tg * 4];
            float av[4] = {a.x, a.y, a.z, a.w};
            float bv[4] = {b.x, b.y, b.z, b.w};
#pragma unroll
            for (int i = 0; i < 4; ++i)
#pragma unroll
                for (int j = 0; j < 4; ++j) acc[i][j] += av[i] * bv[j];
        }
        __syncthreads();
    }
    float* dst = part + ks * (BB * NGATE);
#pragma unroll
    for (int i = 0; i < 4; ++i) {
        int b = tb * 4 + i;
        float4 o = {acc[i][0], acc[i][1], acc[i][2], acc[i][3]};
        *(float4*)&dst[b * NGATE + g0 + tg * 4] = o;
    }
}

// ---------------- K1b: LSTM pointwise + hproj ----------------
__global__ __launch_bounds__(256) void k_lstm(
    const float* __restrict__ part, const float* __restrict__ cell,
    const float* __restrict__ b_ih, const float* __restrict__ b_hh,
    const float* __restrict__ attn_W, const float* __restrict__ attn_b,
    float* __restrict__ h_out, float* __restrict__ c_out, float* __restrict__ hproj)
{
    const int b = blockIdx.x;
    const int u = threadIdx.x;
    __shared__ float hrow[HID];

    float gi = b_ih[u] + b_hh[u];
    float gf = b_ih[u + 256] + b_hh[u + 256];
    float gg = b_ih[u + 512] + b_hh[u + 512];
    float go = b_ih[u + 768] + b_hh[u + 768];
#pragma unroll
    for (int ks = 0; ks < 4; ++ks) {
        const float* p = part + ks * (BB * NGATE) + b * NGATE;
        gi += p[u];
        gf += p[u + 256];
        gg += p[u + 512];
        go += p[u + 768];
    }
    float c = sigm(gf) * cell[b * HID + u] + sigm(gi) * tanhf(gg);
    float h = tanhf(sigm(go) * tanhf(c));
    c_out[b * HID + u] = c;
    h_out[b * HID + u] = h;
    hrow[u] = h;
    __syncthreads();

    float acc = attn_b[u];
    const float* wr = attn_W + u * 768 + 512;
#pragma unroll 8
    for (int k = 0; k < HID; k += 4) {
        float4 w = *(const float4*)&wr[k];
        acc += hrow[k] * w.x + hrow[k + 1] * w.y + hrow[k + 2] * w.z + hrow[k + 3] * w.w;
    }
    hproj[b * HID + u] = acc;
}

// ---------------- K2: fused attention (scores + chunk softmax + chunk context) ----------------
// grid = 64 b x 4 chunks of 128 s; 512 threads = 8 waves (wave: 32 rows x 128 cols)
__global__ __launch_bounds__(512) void k_attn(
    const float* __restrict__ enc, const ushort* __restrict__ wenc_bf,
    const float* __restrict__ hproj, const float* __restrict__ vvec,
    float* __restrict__ ctxp, float* __restrict__ mls)
{
    const int b  = blockIdx.x >> 2;
    const int chk = blockIdx.x & 3;
    const int s0 = chk * CH;
    const int tid = threadIdx.x;
    const int l = tid & 63;
    const int w = tid >> 6;
    const int wr = w >> 1, wc = w & 1;
    const int brow0 = b * SS;

    __shared__ ushort Asm[CH * 64];     // 16 KB, XOR-swizzled in 16B units
    __shared__ ushort Bsm[256 * 64];    // 32 KB
    __shared__ float epart[CH][2];
    __shared__ float es[CH];
    __shared__ float ps[CH];
    __shared__ float red[2];

    f32x4 acc[2][8];
#pragma unroll
    for (int mf = 0; mf < 2; ++mf)
#pragma unroll
        for (int nf = 0; nf < 8; ++nf) acc[mf][nf] = (f32x4){0.f, 0.f, 0.f, 0.f};

    for (int kc = 0; kc < F2H; kc += 64) {
        // stage A: 128 rows x 64 k, fp32 -> bf16 in regs, swizzled ds_write
#pragma unroll
        for (int i = 0; i < 2; ++i) {
            int u = i * 512 + tid;          // 16B-unit index (1024 total)
            int row = u >> 3, cp = u & 7;
            int srow = s0 + row;
            bf16x8 o;
            if (srow < SS) {
                const float4* sp = (const float4*)&enc[((size_t)(brow0 + srow)) * F2H + kc + cp * 8];
                float4 f0 = sp[0], f1 = sp[1];
                o[0] = (short)f2bf(f0.x); o[1] = (short)f2bf(f0.y);
                o[2] = (short)f2bf(f0.z); o[3] = (short)f2bf(f0.w);
                o[4] = (short)f2bf(f1.x); o[5] = (short)f2bf(f1.y);
                o[6] = (short)f2bf(f1.z); o[7] = (short)f2bf(f1.w);
            } else {
                o = (bf16x8){0,0,0,0,0,0,0,0};
            }
            *(bf16x8*)&Asm[row * 64 + ((cp ^ (row & 7)) * 8)] = o;
        }
        // stage B: 256 rows x 64 k bf16 via global_load_lds (linear dest, pre-swz src)
#pragma unroll
        for (int i = 0; i < 4; ++i) {
            int s = (w * 4 + i) * 64 + l;
            int row = s >> 3, cp = s & 7;
            int cl = cp ^ (row & 7);
            const ushort* src = wenc_bf + (size_t)row * F2H + kc + cl * 8;
            __builtin_amdgcn_global_load_lds(
                (const __attribute__((address_space(1))) uint32_t*)src,
                (__attribute__((address_space(3))) uint32_t*)(Bsm + (w * 4 + i) * 512),
                16, 0, 0);
        }
        __syncthreads();
#pragma unroll
        for (int ks = 0; ks < 2; ++ks) {
            bf16x8 af[2], bfr[8];
#pragma unroll
            for (int mf = 0; mf < 2; ++mf) {
                int row = wr * 32 + mf * 16 + (l & 15);
                int c = ks * 4 + (l >> 4);
                af[mf] = *(const bf16x8*)&Asm[row * 64 + ((c ^ (row & 7)) * 8)];
            }
#pragma unroll
            for (int nf = 0; nf < 8; ++nf) {
                int row = wc * 128 + nf * 16 + (l & 15);
                int c = ks * 4 + (l >> 4);
                bfr[nf] = *(const bf16x8*)&Bsm[row * 64 + ((c ^ (row & 7)) * 8)];
            }
#pragma unroll
            for (int mf = 0; mf < 2; ++mf)
#pragma unroll
                for (int nf = 0; nf < 8; ++nf)
                    acc[mf][nf] = __builtin_amdgcn_mfma_f32_16x16x32_bf16(
                        af[mf], bfr[nf], acc[mf][nf], 0, 0, 0);
        }
        __syncthreads();
    }

    // epilogue: + hproj, tanh, dot v, 16-lane reduce
    float vv[8];
#pragma unroll
    for (int nf = 0; nf < 8; ++nf) vv[nf] = vvec[wc * 128 + nf * 16 + (l & 15)];
    const float* hp = hproj + b * HID;

#pragma unroll
    for (int mf = 0; mf < 2; ++mf) {
#pragma unroll
        for (int r = 0; r < 4; ++r) {
            int row = wr * 32 + mf * 16 + (l >> 4) * 4 + r;
            float p = 0.0f;
#pragma unroll
            for (int nf = 0; nf < 8; ++nf) {
                int col = wc * 128 + nf * 16 + (l & 15);
                p += vv[nf] * ftanh(acc[mf][nf][r] + hp[col]);
            }
#pragma unroll
            for (int off = 8; off >= 1; off >>= 1) p += __shfl_xor(p, off);
            if ((l & 15) == 0) epart[row][wc] = p;
        }
    }
    __syncthreads();

    // chunk softmax partial
    if (tid < CH) {
        int s = s0 + tid;
        es[tid] = (s < SS) ? (epart[tid][0] + epart[tid][1]) : -1e30f;
    }
    __syncthreads();
    if (tid < 64) {
        float m2 = fmaxf(es[tid], es[tid + 64]);
#pragma unroll
        for (int off = 32; off >= 1; off >>= 1) m2 = fmaxf(m2, __shfl_xor(m2, off));
        if (tid == 0) red[0] = m2;
    }
    __syncthreads();
    if (tid < CH) ps[tid] = __expf(es[tid] - red[0]);
    __syncthreads();
    if (tid < 64) {
        float s2 = ps[tid] + ps[tid + 64];
#pragma unroll
        for (int off = 32; off >= 1; off >>= 1) s2 += __shfl_xor(s2, off);
        if (tid == 0) red[1] = s2;
    }
    __syncthreads();
    if (tid == 0) {
        mls[(b * 4 + chk) * 2 + 0] = red[0];
        mls[(b * 4 + chk) * 2 + 1] = red[1];
    }

    // chunk context partial: f = tid, fp32 enc (L2-resident after GEMM pass)
    const float* ep = enc + ((size_t)(brow0 + s0)) * F2H + tid;
    const int smax = (s0 + CH <= SS) ? CH : (SS - s0);   // 128 or 16
    float a0 = 0.f, a1 = 0.f, a2 = 0.f, a3 = 0.f;
    for (int s = 0; s < smax; s += 4) {
        a0 += ps[s + 0] * ep[(size_t)(s + 0) * F2H];
        a1 += ps[s + 1] * ep[(size_t)(s + 1) * F2H];
        a2 += ps[s + 2] * ep[(size_t)(s + 2) * F2H];
        a3 += ps[s + 3] * ep[(size_t)(s + 3) * F2H];
    }
    ctxp[((size_t)(b * 4 + chk)) * F2H + tid] = (a0 + a1) + (a2 + a3);
}

// ---------------- K3: combine chunks + concat + projection ----------------
__global__ __launch_bounds__(256) void k_comb(
    const float* __restrict__ ctxp, const float* __restrict__ mls,
    const float* __restrict__ hvals, const float* __restrict__ proj_W,
    const float* __restrict__ proj_b, float* __restrict__ catp)
{
    const int b = blockIdx.x;
    const int j = threadIdx.x;
    __shared__ float cat[768];

    float m[4], lv[4];
#pragma unroll
    for (int c = 0; c < 4; ++c) {
        m[c]  = mls[(b * 4 + c) * 2 + 0];
        lv[c] = mls[(b * 4 + c) * 2 + 1];
    }
    float ms = fmaxf(fmaxf(m[0], m[1]), fmaxf(m[2], m[3]));
    float wgt[4], L = 0.f;
#pragma unroll
    for (int c = 0; c < 4; ++c) { wgt[c] = __expf(m[c] - ms); L += lv[c] * wgt[c]; }
    float inv = 1.0f / L;

#pragma unroll
    for (int p = 0; p < 2; ++p) {
        int f = j + p * 256;
        float s = 0.f;
#pragma unroll
        for (int c = 0; c < 4; ++c) s += ctxp[((size_t)(b * 4 + c)) * F2H + f] * wgt[c];
        cat[f] = s * inv;
    }
    cat[F2H + j] = hvals[b * HID + j];
    __syncthreads();

    float acc = proj_b[j];
    const float* wr = proj_W + j * 768;
#pragma unroll 8
    for (int k = 0; k < 768; k += 4) {
        float4 wv = *(const float4*)&wr[k];
        acc += cat[k] * wv.x + cat[k + 1] * wv.y + cat[k + 2] * wv.z + cat[k + 3] * wv.w;
    }
    catp[b * HID + j] = acc;
}

// ---------------- K6: output GEMM via bf16 MFMA ----------------
__global__ __launch_bounds__(256) void k_out(
    const float* __restrict__ catp, const float* __restrict__ out_W,
    const float* __restrict__ out_b, float* __restrict__ wd)
{
    __shared__ ushort Cs[64 * 256];

    const int tid = threadIdx.x;
    const int l = tid & 63;
    const int w = tid >> 6;

#pragma unroll
    for (int i = 0; i < 8; ++i) {
        int u = i * 256 + tid;
        int n = u >> 5, c16 = u & 31;
        const float4* src = (const float4*)&catp[n * HID + c16 * 8];
        float4 f0 = src[0], f1 = src[1];
        bf16x8 o;
        o[0] = (short)f2bf(f0.x); o[1] = (short)f2bf(f0.y);
        o[2] = (short)f2bf(f0.z); o[3] = (short)f2bf(f0.w);
        o[4] = (short)f2bf(f1.x); o[5] = (short)f2bf(f1.y);
        o[6] = (short)f2bf(f1.z); o[7] = (short)f2bf(f1.w);
        *(bf16x8*)&Cs[n * 256 + ((c16 ^ (n & 7)) * 8)] = o;
    }
    __syncthreads();

    const int vw = blockIdx.x * 128 + w * 32;
    const int q = l >> 4;
    const int ln = l & 15;

    f32x4 acc[4][2];
#pragma unroll
    for (int af = 0; af < 4; ++af)
#pragma unroll
        for (int nf = 0; nf < 2; ++nf) acc[af][nf] = (f32x4){0.f, 0.f, 0.f, 0.f};

    int vr[2];
#pragma unroll
    for (int nf = 0; nf < 2; ++nf) {
        int v = vw + nf * 16 + ln;
        vr[nf] = v < VOC ? v : VOC - 1;
    }

#pragma unroll
    for (int s = 0; s < 8; ++s) {
        const int k = s * 32 + q * 8;
        bf16x8 bfr[2];
#pragma unroll
        for (int nf = 0; nf < 2; ++nf) {
            const float4* p = (const float4*)&out_W[(size_t)vr[nf] * HID + k];
            float4 f0 = p[0], f1 = p[1];
            bf16x8 o;
            o[0] = (short)f2bf(f0.x); o[1] = (short)f2bf(f0.y);
            o[2] = (short)f2bf(f0.z); o[3] = (short)f2bf(f0.w);
            o[4] = (short)f2bf(f1.x); o[5] = (short)f2bf(f1.y);
            o[6] = (short)f2bf(f1.z); o[7] = (short)f2bf(f1.w);
            bfr[nf] = o;
        }
#pragma unroll
        for (int af = 0; af < 4; ++af) {
            int row = af * 16 + ln;
            int c16 = (s * 4 + q) ^ (row & 7);
            bf16x8 a = *(const bf16x8*)&Cs[row * 256 + c16 * 8];
#pragma unroll
            for (int nf = 0; nf < 2; ++nf)
                acc[af][nf] = __builtin_amdgcn_mfma_f32_16x16x32_bf16(
                    a, bfr[nf], acc[af][nf], 0, 0, 0);
        }
    }

#pragma unroll
    for (int nf = 0; nf < 2; ++nf) {
        int v = vw + nf * 16 + ln;
        if (v < VOC) {
            float bias = out_b[v];
#pragma unroll
            for (int af = 0; af < 4; ++af) {
                int b = af * 16 + q * 4;
#pragma unroll
                for (int r = 0; r < 4; ++r)
                    wd[(size_t)(b + r) * VOC + v] = acc[af][nf][r] + bias;
            }
        }
    }
}

extern "C" void kernel_launch(void* const* d_in, const int* in_sizes, int n_in,
                              void* d_out, int out_size, void* d_ws, size_t ws_size,
                              hipStream_t stream) {
    const int*   word   = (const int*)  d_in[0];
    const float* hidden = (const float*)d_in[1];
    const float* cell   = (const float*)d_in[2];
    const float* enc    = (const float*)d_in[3];
    const float* embed  = (const float*)d_in[5];
    const float* W_ih   = (const float*)d_in[6];
    const float* W_hh   = (const float*)d_in[7];
    const float* b_ih   = (const float*)d_in[8];
    const float* b_hh   = (const float*)d_in[9];
    const float* attn_W = (const float*)d_in[10];
    const float* attn_b = (const float*)d_in[11];
    const float* vvec   = (const float*)d_in[12];
    const float* proj_W = (const float*)d_in[13];
    const float* proj_b = (const float*)d_in[14];
    const float* out_W  = (const float*)d_in[15];
    const float* out_b  = (const float*)d_in[16];

    float* wd  = (float*)d_out;
    float* h_o = wd + (size_t)BB * VOC;
    float* c_o = h_o + BB * HID;

    float* ws    = (float*)d_ws;
    float* part  = ws;                        // 262144
    float* hproj = part + 262144;             // 16384
    float* catp  = hproj + 16384;             // 16384
    float* ctxp  = catp + 16384;              // 64*4*512 = 131072
    float* mls   = ctxp + 131072;             // 512
    ushort* wenc_bf = (ushort*)(mls + 512);   // 131072 ushorts

    k_prepw<<<16, 256, 0, stream>>>(attn_W, wenc_bf);
    k_gates<<<dim3(16, 4), 256, 0, stream>>>(word, hidden, embed, W_ih, W_hh, part);
    k_lstm<<<64, 256, 0, stream>>>(part, cell, b_ih, b_hh, attn_W, attn_b, h_o, c_o, hproj);
    k_attn<<<256, 512, 0, stream>>>(enc, wenc_bf, hproj, vvec, ctxp, mls);
    k_comb<<<64, 256, 0, stream>>>(ctxp, mls, h_o, proj_W, proj_b, catp);
    k_out<<<391, 256, 0, stream>>>(catp, out_W, out_b, wd);
}

// Round 5
// 92.632 us; speedup vs baseline: 2.4033x; 1.0945x over previous
//
#include <hip/hip_runtime.h>
#include <math.h>

#define BB 64
#define SS 400
#define F2H 512
#define HID 256
#define EMB 128
#define NGATE 1024
#define VOC 50000
#define CH 64
#define NCHK 7
#define KC 32
#define NKC 16

typedef short bf16x8 __attribute__((ext_vector_type(8)));
typedef float f32x4 __attribute__((ext_vector_type(4)));

__device__ __forceinline__ float sigm(float x) { return 1.0f / (1.0f + __expf(-x)); }

__device__ __forceinline__ float ftanh(float x) {
    x = fminf(fmaxf(x, -15.0f), 15.0f);
    float t = __expf(2.0f * x);
    return (t - 1.0f) / (t + 1.0f);
}

__device__ __forceinline__ ushort f2bf(float x) {
    uint32_t u = __float_as_uint(x);
    uint32_t r = u + 0x7FFFu + ((u >> 16) & 1u);
    return (ushort)(r >> 16);
}

__device__ __forceinline__ bf16x8 cvt8(float4 a, float4 b) {
    bf16x8 o;
    o[0] = (short)f2bf(a.x); o[1] = (short)f2bf(a.y);
    o[2] = (short)f2bf(a.z); o[3] = (short)f2bf(a.w);
    o[4] = (short)f2bf(b.x); o[5] = (short)f2bf(b.y);
    o[6] = (short)f2bf(b.z); o[7] = (short)f2bf(b.w);
    return o;
}

// ---------------- K1a: gates partial GEMM + fused wenc prep ----------------
// grid (16, 5): y<4 -> gates k-split; y==4 -> wenc bf16 prep
__global__ __launch_bounds__(256) void k_gates(
    const int* __restrict__ word, const float* __restrict__ hidden,
    const float* __restrict__ embed, const float* __restrict__ W_ih,
    const float* __restrict__ W_hh, float* __restrict__ part,
    const float* __restrict__ attn_W, ushort* __restrict__ wenc_bf)
{
    const int gt = blockIdx.x;
    const int ks = blockIdx.y;
    const int tid = threadIdx.x;

    if (ks == 4) {   // wenc prep: 16 blocks x 256 thr x 8 float4
        int i0 = gt * 2048 + tid;
#pragma unroll
        for (int r = 0; r < 8; ++r) {
            int i = i0 + r * 256;
            int row = i >> 7, c = i & 127;
            float4 f = *(const float4*)&attn_W[row * 768 + c * 4];
            ushort4 o = make_ushort4(f2bf(f.x), f2bf(f.y), f2bf(f.z), f2bf(f.w));
            ((ushort4*)wenc_bf)[i] = o;
        }
        return;
    }

    __shared__ float As[32 * 68];
    __shared__ float Bs[32 * 68];
    const int g0 = gt * 64;
    const int k0 = ks * 96;
    float acc[4][4];
#pragma unroll
    for (int i = 0; i < 4; ++i)
#pragma unroll
        for (int j = 0; j < 4; ++j) acc[i][j] = 0.0f;

    const int tb = tid >> 4;
    const int tg = tid & 15;
    const int srow = tid >> 3;
    const int skk = (tid & 7) * 4;

    for (int c = 0; c < 3; ++c) {
        const int kc = k0 + c * 32;
#pragma unroll
        for (int p = 0; p < 2; ++p) {
            int rr = srow + p * 32;
            int gk = kc + skk;
            float4 f;
            if (gk < EMB) {
                int w = word[rr];
                f = *(const float4*)&embed[w * EMB + gk];
            } else {
                f = *(const float4*)&hidden[rr * HID + gk - EMB];
            }
            As[(skk + 0) * 68 + rr] = f.x;
            As[(skk + 1) * 68 + rr] = f.y;
            As[(skk + 2) * 68 + rr] = f.z;
            As[(skk + 3) * 68 + rr] = f.w;
        }
#pragma unroll
        for (int p = 0; p < 2; ++p) {
            int nn = srow + p * 32;
            int g = g0 + nn;
            int gk = kc + skk;
            float4 f;
            if (gk < EMB) f = *(const float4*)&W_ih[g * EMB + gk];
            else          f = *(const float4*)&W_hh[g * HID + gk - EMB];
            Bs[(skk + 0) * 68 + nn] = f.x;
            Bs[(skk + 1) * 68 + nn] = f.y;
            Bs[(skk + 2) * 68 + nn] = f.z;
            Bs[(skk + 3) * 68 + nn] = f.w;
        }
        __syncthreads();
#pragma unroll 8
        for (int k = 0; k < 32; ++k) {
            float4 a = *(const float4*)&As[k * 68 + tb * 4];
            float4 b = *(const float4*)&Bs[k * 68 + tg * 4];
            float av[4] = {a.x, a.y, a.z, a.w};
            float bv[4] = {b.x, b.y, b.z, b.w};
#pragma unroll
            for (int i = 0; i < 4; ++i)
#pragma unroll
                for (int j = 0; j < 4; ++j) acc[i][j] += av[i] * bv[j];
        }
        __syncthreads();
    }
    float* dst = part + ks * (BB * NGATE);
#pragma unroll
    for (int i = 0; i < 4; ++i) {
        int b = tb * 4 + i;
        float4 o = {acc[i][0], acc[i][1], acc[i][2], acc[i][3]};
        *(float4*)&dst[b * NGATE + g0 + tg * 4] = o;
    }
}

// ---------------- K1b: LSTM pointwise + hproj ----------------
__global__ __launch_bounds__(256) void k_lstm(
    const float* __restrict__ part, const float* __restrict__ cell,
    const float* __restrict__ b_ih, const float* __restrict__ b_hh,
    const float* __restrict__ attn_W, const float* __restrict__ attn_b,
    float* __restrict__ h_out, float* __restrict__ c_out, float* __restrict__ hproj)
{
    const int b = blockIdx.x;
    const int u = threadIdx.x;
    __shared__ float hrow[HID];

    float gi = b_ih[u] + b_hh[u];
    float gf = b_ih[u + 256] + b_hh[u + 256];
    float gg = b_ih[u + 512] + b_hh[u + 512];
    float go = b_ih[u + 768] + b_hh[u + 768];
#pragma unroll
    for (int ks = 0; ks < 4; ++ks) {
        const float* p = part + ks * (BB * NGATE) + b * NGATE;
        gi += p[u];
        gf += p[u + 256];
        gg += p[u + 512];
        go += p[u + 768];
    }
    float c = sigm(gf) * cell[b * HID + u] + sigm(gi) * tanhf(gg);
    float h = tanhf(sigm(go) * tanhf(c));
    c_out[b * HID + u] = c;
    h_out[b * HID + u] = h;
    hrow[u] = h;
    __syncthreads();

    float acc = attn_b[u];
    const float* wr = attn_W + u * 768 + 512;
#pragma unroll 8
    for (int k = 0; k < HID; k += 4) {
        float4 w = *(const float4*)&wr[k];
        acc += hrow[k] * w.x + hrow[k + 1] * w.y + hrow[k + 2] * w.z + hrow[k + 3] * w.w;
    }
    hproj[b * HID + u] = acc;
}

// ---------------- K2: fused attention, pipelined ----------------
// grid = 64 b x 7 chunks of 64 s; 256 threads = 4 waves (wave: 32 rows x 128 cols)
// double-buffered: A reg-staged (pad-40), B via global_load_lds (pre-swz src)
__global__ __launch_bounds__(256) void k_attn(
    const float* __restrict__ enc, const ushort* __restrict__ wenc_bf,
    const float* __restrict__ hproj, const float* __restrict__ vvec,
    float* __restrict__ ctxp, float* __restrict__ mls)
{
    const int b   = blockIdx.x / NCHK;
    const int chk = blockIdx.x % NCHK;
    const int s0  = chk * CH;
    const int tid = threadIdx.x;
    const int l = tid & 63;
    const int w = tid >> 6;
    const int wr = w >> 1, wc = w & 1;
    const int brow0 = b * SS;

    __shared__ ushort Asm[2][CH * 40];     // pad stride 40 -> 2-way max
    __shared__ ushort Bsm[2][256 * KC];    // rows 64B, unit-XOR swizzled
    __shared__ float epart[CH][2];
    __shared__ float ps[CH];

    const int arow = tid >> 2;
    const int acolu = tid & 3;
    const int srow = s0 + arow;
    const bool aval = srow < SS;
    const float* abase = enc + (size_t)(brow0 + (aval ? srow : 0)) * F2H + acolu * 8;
    const int busrc = ((l & 3) ^ ((l >> 3) & 3)) * 8;

    f32x4 acc[2][8];
#pragma unroll
    for (int mf = 0; mf < 2; ++mf)
#pragma unroll
        for (int nf = 0; nf < 8; ++nf) acc[mf][nf] = (f32x4){0.f, 0.f, 0.f, 0.f};

    // prologue: stage iter 0 -> buf 0
    {
#pragma unroll
        for (int i = 0; i < 4; ++i) {
            int j = w * 4 + i;
            int row = j * 16 + (l >> 2);
            const ushort* src = wenc_bf + (size_t)row * F2H + busrc;
            __builtin_amdgcn_global_load_lds(
                (const __attribute__((address_space(1))) uint32_t*)src,
                (__attribute__((address_space(3))) uint32_t*)(&Bsm[0][j * 512]),
                16, 0, 0);
        }
        float4 a0 = {0,0,0,0}, a1 = {0,0,0,0};
        if (aval) { a0 = ((const float4*)abase)[0]; a1 = ((const float4*)abase)[1]; }
        *(bf16x8*)&Asm[0][arow * 40 + acolu * 8] = cvt8(a0, a1);
    }
    __syncthreads();

    int buf = 0;
    for (int it = 0; it < NKC; ++it) {
        const int nkc = (it + 1) * KC;
        const bool pf = (it + 1) < NKC;
        float4 a0 = {0,0,0,0}, a1 = {0,0,0,0};
        if (pf) {
            if (aval) {
                a0 = *(const float4*)(abase + nkc);
                a1 = *(const float4*)(abase + nkc + 4);
            }
#pragma unroll
            for (int i = 0; i < 4; ++i) {
                int j = w * 4 + i;
                int row = j * 16 + (l >> 2);
                const ushort* src = wenc_bf + (size_t)row * F2H + nkc + busrc;
                __builtin_amdgcn_global_load_lds(
                    (const __attribute__((address_space(1))) uint32_t*)src,
                    (__attribute__((address_space(3))) uint32_t*)(&Bsm[buf ^ 1][j * 512]),
                    16, 0, 0);
            }
        }
        // compute on buf
        bf16x8 af[2], bfr[8];
#pragma unroll
        for (int mf = 0; mf < 2; ++mf) {
            int row = wr * 32 + mf * 16 + (l & 15);
            af[mf] = *(const bf16x8*)&Asm[buf][row * 40 + (l >> 4) * 8];
        }
#pragma unroll
        for (int nf = 0; nf < 8; ++nf) {
            int row = wc * 128 + nf * 16 + (l & 15);
            int u = (l >> 4) ^ ((l >> 1) & 3);
            bfr[nf] = *(const bf16x8*)&Bsm[buf][row * KC + u * 8];
        }
#pragma unroll
        for (int mf = 0; mf < 2; ++mf)
#pragma unroll
            for (int nf = 0; nf < 8; ++nf)
                acc[mf][nf] = __builtin_amdgcn_mfma_f32_16x16x32_bf16(
                    af[mf], bfr[nf], acc[mf][nf], 0, 0, 0);
        if (pf) {
            *(bf16x8*)&Asm[buf ^ 1][arow * 40 + acolu * 8] = cvt8(a0, a1);
        }
        __syncthreads();
        buf ^= 1;
    }

    // epilogue: + hproj, tanh, dot v, 16-lane reduce
    float vv[8];
#pragma unroll
    for (int nf = 0; nf < 8; ++nf) vv[nf] = vvec[wc * 128 + nf * 16 + (l & 15)];
    const float* hp = hproj + b * HID;

#pragma unroll
    for (int mf = 0; mf < 2; ++mf) {
#pragma unroll
        for (int r = 0; r < 4; ++r) {
            int row = wr * 32 + mf * 16 + (l >> 4) * 4 + r;
            float p = 0.0f;
#pragma unroll
            for (int nf = 0; nf < 8; ++nf) {
                int col = wc * 128 + nf * 16 + (l & 15);
                p += vv[nf] * ftanh(acc[mf][nf][r] + hp[col]);
            }
#pragma unroll
            for (int off = 8; off >= 1; off >>= 1) p += __shfl_xor(p, off);
            if ((l & 15) == 0) epart[row][wc] = p;
        }
    }
    __syncthreads();

    // chunk softmax partial (one wave: tid < 64)
    if (tid < 64) {
        int s = s0 + tid;
        float es = (s < SS) ? (epart[tid][0] + epart[tid][1]) : -1e30f;
        float m = es;
#pragma unroll
        for (int off = 32; off >= 1; off >>= 1) m = fmaxf(m, __shfl_xor(m, off));
        float p = __expf(es - m);
        ps[tid] = p;
        float sum = p;
#pragma unroll
        for (int off = 32; off >= 1; off >>= 1) sum += __shfl_xor(sum, off);
        if (tid == 0) {
            mls[(b * NCHK + chk) * 2 + 0] = m;
            mls[(b * NCHK + chk) * 2 + 1] = sum;
        }
    }
    __syncthreads();

    // chunk context partial
    const float* ep = enc + (size_t)(brow0 + s0) * F2H;
    const int smax = (SS - s0 < CH) ? (SS - s0) : CH;
    float c0 = 0.f, c1 = 0.f;
    for (int s = 0; s < smax; s += 4) {
#pragma unroll
        for (int q2 = 0; q2 < 4; ++q2) {
            float p = ps[s + q2];
            c0 += p * ep[(size_t)(s + q2) * F2H + tid];
            c1 += p * ep[(size_t)(s + q2) * F2H + tid + 256];
        }
    }
    ctxp[(size_t)(b * NCHK + chk) * F2H + tid] = c0;
    ctxp[(size_t)(b * NCHK + chk) * F2H + tid + 256] = c1;
}

// ---------------- K3: combine chunks + concat + projection ----------------
__global__ __launch_bounds__(256) void k_comb(
    const float* __restrict__ ctxp, const float* __restrict__ mls,
    const float* __restrict__ hvals, const float* __restrict__ proj_W,
    const float* __restrict__ proj_b, float* __restrict__ catp)
{
    const int b = blockIdx.x;
    const int j = threadIdx.x;
    __shared__ float cat[768];

    float m[NCHK], lv[NCHK];
#pragma unroll
    for (int c = 0; c < NCHK; ++c) {
        m[c]  = mls[(b * NCHK + c) * 2 + 0];
        lv[c] = mls[(b * NCHK + c) * 2 + 1];
    }
    float ms = m[0];
#pragma unroll
    for (int c = 1; c < NCHK; ++c) ms = fmaxf(ms, m[c]);
    float wgt[NCHK], L = 0.f;
#pragma unroll
    for (int c = 0; c < NCHK; ++c) { wgt[c] = __expf(m[c] - ms); L += lv[c] * wgt[c]; }
    float inv = 1.0f / L;

#pragma unroll
    for (int p = 0; p < 2; ++p) {
        int f = j + p * 256;
        float s = 0.f;
#pragma unroll
        for (int c = 0; c < NCHK; ++c) s += ctxp[((size_t)(b * NCHK + c)) * F2H + f] * wgt[c];
        cat[f] = s * inv;
    }
    cat[F2H + j] = hvals[b * HID + j];
    __syncthreads();

    float acc = proj_b[j];
    const float* wr = proj_W + j * 768;
#pragma unroll 8
    for (int k = 0; k < 768; k += 4) {
        float4 wv = *(const float4*)&wr[k];
        acc += cat[k] * wv.x + cat[k + 1] * wv.y + cat[k + 2] * wv.z + cat[k + 3] * wv.w;
    }
    catp[b * HID + j] = acc;
}

// ---------------- K6: output GEMM via bf16 MFMA, prefetched ----------------
__global__ __launch_bounds__(256) void k_out(
    const float* __restrict__ catp, const float* __restrict__ out_W,
    const float* __restrict__ out_b, float* __restrict__ wd)
{
    __shared__ ushort Cs[64 * 256];

    const int tid = threadIdx.x;
    const int l = tid & 63;
    const int w = tid >> 6;

#pragma unroll
    for (int i = 0; i < 8; ++i) {
        int u = i * 256 + tid;
        int n = u >> 5, c16 = u & 31;
        const float4* src = (const float4*)&catp[n * HID + c16 * 8];
        float4 f0 = src[0], f1 = src[1];
        *(bf16x8*)&Cs[n * 256 + ((c16 ^ (n & 7)) * 8)] = cvt8(f0, f1);
    }
    __syncthreads();

    const int vw = blockIdx.x * 128 + w * 32;
    const int q = l >> 4;
    const int ln = l & 15;

    f32x4 acc[4][2];
#pragma unroll
    for (int af = 0; af < 4; ++af)
#pragma unroll
        for (int nf = 0; nf < 2; ++nf) acc[af][nf] = (f32x4){0.f, 0.f, 0.f, 0.f};

    int vr[2];
#pragma unroll
    for (int nf = 0; nf < 2; ++nf) {
        int v = vw + nf * 16 + ln;
        vr[nf] = v < VOC ? v : VOC - 1;
    }
    const float* pw0 = out_W + (size_t)vr[0] * HID + q * 8;
    const float* pw1 = out_W + (size_t)vr[1] * HID + q * 8;

    float4 c00 = ((const float4*)pw0)[0];
    float4 c01 = ((const float4*)pw0)[1];
    float4 c10 = ((const float4*)pw1)[0];
    float4 c11 = ((const float4*)pw1)[1];

#pragma unroll
    for (int s = 0; s < 8; ++s) {
        float4 n00, n01, n10, n11;
        if (s < 7) {
            const float4* q0 = (const float4*)(pw0 + (s + 1) * 32);
            const float4* q1 = (const float4*)(pw1 + (s + 1) * 32);
            n00 = q0[0]; n01 = q0[1];
            n10 = q1[0]; n11 = q1[1];
        }
        bf16x8 bfr0 = cvt8(c00, c01);
        bf16x8 bfr1 = cvt8(c10, c11);
#pragma unroll
        for (int af = 0; af < 4; ++af) {
            int row = af * 16 + ln;
            int c16 = (s * 4 + q) ^ (row & 7);
            bf16x8 a = *(const bf16x8*)&Cs[row * 256 + c16 * 8];
            acc[af][0] = __builtin_amdgcn_mfma_f32_16x16x32_bf16(a, bfr0, acc[af][0], 0, 0, 0);
            acc[af][1] = __builtin_amdgcn_mfma_f32_16x16x32_bf16(a, bfr1, acc[af][1], 0, 0, 0);
        }
        if (s < 7) { c00 = n00; c01 = n01; c10 = n10; c11 = n11; }
    }

#pragma unroll
    for (int nf = 0; nf < 2; ++nf) {
        int v = vw + nf * 16 + ln;
        if (v < VOC) {
            float bias = out_b[v];
#pragma unroll
            for (int af = 0; af < 4; ++af) {
                int b = af * 16 + q * 4;
#pragma unroll
                for (int r = 0; r < 4; ++r)
                    wd[(size_t)(b + r) * VOC + v] = acc[af][nf][r] + bias;
            }
        }
    }
}

extern "C" void kernel_launch(void* const* d_in, const int* in_sizes, int n_in,
                              void* d_out, int out_size, void* d_ws, size_t ws_size,
                              hipStream_t stream) {
    const int*   word   = (const int*)  d_in[0];
    const float* hidden = (const float*)d_in[1];
    const float* cell   = (const float*)d_in[2];
    const float* enc    = (const float*)d_in[3];
    const float* embed  = (const float*)d_in[5];
    const float* W_ih   = (const float*)d_in[6];
    const float* W_hh   = (const float*)d_in[7];
    const float* b_ih   = (const float*)d_in[8];
    const float* b_hh   = (const float*)d_in[9];
    const float* attn_W = (const float*)d_in[10];
    const float* attn_b = (const float*)d_in[11];
    const float* vvec   = (const float*)d_in[12];
    const float* proj_W = (const float*)d_in[13];
    const float* proj_b = (const float*)d_in[14];
    const float* out_W  = (const float*)d_in[15];
    const float* out_b  = (const float*)d_in[16];

    float* wd  = (float*)d_out;
    float* h_o = wd + (size_t)BB * VOC;
    float* c_o = h_o + BB * HID;

    float* ws    = (float*)d_ws;
    float* part  = ws;                          // 262144
    float* hproj = part + 262144;               // 16384
    float* catp  = hproj + 16384;               // 16384
    float* ctxp  = catp + 16384;                // 64*7*512 = 229376
    float* mls   = ctxp + 229376;               // 896
    ushort* wenc_bf = (ushort*)(mls + 896);     // 131072 ushorts

    k_gates<<<dim3(16, 5), 256, 0, stream>>>(word, hidden, embed, W_ih, W_hh, part, attn_W, wenc_bf);
    k_lstm<<<64, 256, 0, stream>>>(part, cell, b_ih, b_hh, attn_W, attn_b, h_o, c_o, hproj);
    k_attn<<<BB * NCHK, 256, 0, stream>>>(enc, wenc_bf, hproj, vvec, ctxp, mls);
    k_comb<<<64, 256, 0, stream>>>(ctxp, mls, h_o, proj_W, proj_b, catp);
    k_out<<<391, 256, 0, stream>>>(catp, out_W, out_b, wd);
}